// Round 4
// baseline (1136.133 us; speedup 1.0000x reference)
//
#include <hip/hip_runtime.h>
#include <hip/hip_bf16.h>

#define NB 8
#define NV 200
#define NE 40000
#define NH 128
#define NL 3
#define TILES (NE/64)   // 625

typedef __attribute__((ext_vector_type(8))) __bf16 bf16x8;
typedef __attribute__((ext_vector_type(8))) short s16x8;
typedef __attribute__((ext_vector_type(4))) float f32x4;

__device__ inline float sigmoidf_(float x){ return 1.0f/(1.0f + __expf(-x)); }

// round-to-nearest-even f32 -> bf16 bits
__device__ inline short f2b(float f){
  union{ float f; unsigned u; } v; v.f = f;
  unsigned u = v.u;
  u += 0x7fffu + ((u >> 16) & 1u);
  return (short)(u >> 16);
}
__device__ inline float b2f(short s){
  union{ unsigned u; float f; } v; v.u = ((unsigned)(unsigned short)s) << 16;
  return v.f;
}
// split x ~= hi + lo, both bf16
__device__ inline void splitb(float x, short &hi, short &lo){
  hi = f2b(x);
  lo = f2b(x - b2f(hi));
}

// ---------------- embed ----------------
__global__ __launch_bounds__(256) void k_embed_nodes(
    const float* __restrict__ x, const float* __restrict__ nW,
    const float* __restrict__ nb, float* __restrict__ xh)
{
  int i = blockIdx.x*256 + threadIdx.x;
  if (i >= NB*NV*NH) return;
  int h  = i & (NH-1);
  int bv = i >> 7;
  xh[i] = x[bv*2+0]*nW[h] + x[bv*2+1]*nW[NH+h] + nb[h];
}

__global__ __launch_bounds__(256) void k_embed_edges(
    const float* __restrict__ e, const float* __restrict__ eW,
    const float* __restrict__ eb, float* __restrict__ eh)
{
  int i = blockIdx.x*256 + threadIdx.x;       // over NB*NE*NH/4
  if (i >= NB*NE*NH/4) return;
  int h4 = i & (NH/4 - 1);
  int be = i >> 5;
  float ev = e[be];
  f32x4 w  = *(const f32x4*)(eW + h4*4);
  f32x4 bb = *(const f32x4*)(eb + h4*4);
  f32x4 r;
  #pragma unroll
  for (int j=0;j<4;j++) r[j] = ev*w[j] + bb[j];
  *(f32x4*)(eh + (size_t)be*NH + h4*4) = r;
}

// ---------------- weight transpose to split bf16 (Wt[n][k] = W[k][n]) ----------------
// layout: Wt + m*NH*NH        -> hi of matrix m   (m = 0..2: A_W layers, 3: out_W1)
//         Wt + (4+m)*NH*NH    -> lo of matrix m
__global__ __launch_bounds__(256) void k_trans_w(
    const float* __restrict__ AW, const float* __restrict__ oW1,
    short* __restrict__ Wt)
{
  int m = blockIdx.x;                         // 0..3
  const float* src = (m < 3) ? (AW + m*NH*NH) : oW1;
  short* dhi = Wt + (size_t)m*NH*NH;
  short* dlo = Wt + (size_t)(4+m)*NH*NH;
  for (int i = threadIdx.x; i < NH*NH; i += 256){
    int n = i >> 7, k = i & 127;
    short hi, lo;
    splitb(src[k*NH + n], hi, lo);
    dhi[i] = hi; dlo[i] = lo;
  }
}

// ---------------- CSR build ----------------
__global__ __launch_bounds__(256) void k_zero(int* __restrict__ p, int n){
  int i = blockIdx.x*256 + threadIdx.x;
  if (i < n) p[i] = 0;
}

__global__ __launch_bounds__(256) void k_count(const int* __restrict__ ei, int* __restrict__ counts){
  int i = blockIdx.x*256 + threadIdx.x;
  if (i >= NB*NE) return;
  int b = i / NE, e = i % NE;
  int dv = ei[b*2*NE + NE + e];
  atomicAdd(&counts[b*NV + dv], 1);
}

__global__ void k_scan(const int* __restrict__ counts, int* __restrict__ offs, int* __restrict__ cursor){
  int b = blockIdx.x;
  if (threadIdx.x == 0){
    int run = 0;
    for (int v=0; v<NV; v++){
      offs[b*(NV+1)+v] = run;
      cursor[b*NV+v]   = run;
      run += counts[b*NV+v];
    }
    offs[b*(NV+1)+NV] = run;
  }
}

__global__ __launch_bounds__(256) void k_scatter(const int* __restrict__ ei, int* __restrict__ cursor, int* __restrict__ csr){
  int i = blockIdx.x*256 + threadIdx.x;
  if (i >= NB*NE) return;
  int b = i / NE, e = i % NE;
  int dv = ei[b*2*NE + NE + e];
  int pos = atomicAdd(&cursor[b*NV + dv], 1);
  csr[(size_t)b*NE + pos] = e;
}

// ---------------- per-layer node matmuls: vx,bx,cx,ux ----------------
__global__ __launch_bounds__(256) void k_node_mm(
    const float* __restrict__ xh,
    const float* __restrict__ VWl, const float* __restrict__ Vbl,
    const float* __restrict__ BWl, const float* __restrict__ Bbl,
    const float* __restrict__ CWl, const float* __restrict__ Cbl,
    const float* __restrict__ UWl, const float* __restrict__ Ubl,
    float* __restrict__ vx, float* __restrict__ bx,
    float* __restrict__ cx, float* __restrict__ ux)
{
  __shared__ float sx[NH];
  int b = blockIdx.x / NV, v = blockIdx.x % NV;
  const float* xr = xh + ((size_t)b*NV + v)*NH;
  if (threadIdx.x < NH) sx[threadIdx.x] = xr[threadIdx.x];
  __syncthreads();
  #pragma unroll
  for (int pass=0; pass<2; pass++){
    int t = threadIdx.x + pass*256;
    int mat = t >> 7, h = t & 127;
    const float* W = (mat==0) ? VWl : (mat==1) ? BWl : (mat==2) ? CWl : UWl;
    const float* bs = (mat==0) ? Vbl : (mat==1) ? Bbl : (mat==2) ? Cbl : Ubl;
    float* op = (mat==0) ? vx : (mat==1) ? bx : (mat==2) ? cx : ux;
    float acc = bs[h];
    #pragma unroll 8
    for (int k=0;k<NH;k++) acc += sx[k]*W[k*NH + h];
    op[((size_t)b*NV + v)*NH + h] = acc;
  }
}

// ---------------- aggregation: agg_part[v] = partial sum_{e: dst=v} sigmoid(eh[e]) * vx[src[e]]
// two blocks per (b,v), each does half the CSR range; node_update sums the parts.
__global__ __launch_bounds__(128) void k_agg(
    const float* __restrict__ eh, const float* __restrict__ vx,
    const int* __restrict__ ei, const int* __restrict__ csr,
    const int* __restrict__ offs, float* __restrict__ agg)
{
  int part = blockIdx.x & 1;
  int bv   = blockIdx.x >> 1;
  int b = bv / NV, v = bv % NV;
  int h = threadIdx.x;
  const int* srcp  = ei + b*2*NE;
  const int* csrg  = csr + (size_t)b*NE;
  const float* ehg = eh + (size_t)b*NE*NH;
  const float* vxg = vx + (size_t)b*NV*NH;
  int beg = offs[b*(NV+1)+v], end = offs[b*(NV+1)+v+1];
  int mid = (beg + end) >> 1;
  int i    = part ? mid : beg;
  int stop = part ? end : mid;
  float acc = 0.f;
  for (; i+8 <= stop; i += 8){
    int   eb[8], sb[8];
    float a[8], w[8];
    #pragma unroll
    for (int j=0;j<8;j++) eb[j] = csrg[i+j];
    #pragma unroll
    for (int j=0;j<8;j++) sb[j] = srcp[eb[j]];
    #pragma unroll
    for (int j=0;j<8;j++) a[j] = ehg[(size_t)eb[j]*NH + h];
    #pragma unroll
    for (int j=0;j<8;j++) w[j] = vxg[sb[j]*NH + h];
    #pragma unroll
    for (int j=0;j<8;j++) acc += sigmoidf_(a[j]) * w[j];
  }
  for (; i < stop; i++){
    int e0 = csrg[i]; int s0 = srcp[e0];
    acc += sigmoidf_(ehg[(size_t)e0*NH+h]) * vxg[s0*NH+h];
  }
  agg[((size_t)part*NB*NV + (size_t)b*NV + v)*NH + h] = acc;
}

// ---------------- edge update: eh += relu(eh@A_W + A_b + bx[src] + cx[dst]) ----------------
// Operand-swapped MFMA: A = Wt (rows = output h), B = eh^T (cols = edges).
// C/D layout (m89): row = lg*4 + reg -> h within tile (contiguous!), col = l15 -> edge.
// => each lane owns ONE edge (e0+l15) and f32x4-contiguous h-chunks -> vector epilogue.
__global__ __launch_bounds__(256, 4) void k_edge_update(
    float* __restrict__ eh, const short* __restrict__ Wt,
    const float* __restrict__ Ab, const float* __restrict__ bx,
    const float* __restrict__ cx, const int* __restrict__ ei)
{
  int tile = blockIdx.x % TILES;
  int b    = blockIdx.x / TILES;
  int wave = threadIdx.x >> 6;
  int lane = threadIdx.x & 63;
  int l15 = lane & 15, lg = lane >> 4;
  int e0 = tile*64 + wave*16;
  int e  = e0 + l15;
  float* ehg = eh + (size_t)b*NE*NH;
  const short* Whi = Wt;
  const short* Wlo = Wt + 4*NH*NH;

  // indices early (hide latency under frag build + MFMA)
  const int* srcp = ei + b*2*NE;
  int sv = srcp[e], dv = srcp[NE + e];

  // B fragments from eh row e (split): col = l15 (edge), k = kk*32 + lg*8 + t
  const float* bptr = ehg + (size_t)e*NH + lg*8;
  bf16x8 ebh[4], ebl[4];
  #pragma unroll
  for (int kk=0;kk<4;kk++){
    f32x4 p0 = *(const f32x4*)(bptr + kk*32);
    f32x4 p1 = *(const f32x4*)(bptr + kk*32 + 4);
    union{ short s[8]; bf16x8 v; } uh, ul;
    #pragma unroll
    for (int j=0;j<4;j++){
      splitb(p0[j], uh.s[j],   ul.s[j]);
      splitb(p1[j], uh.s[4+j], ul.s[4+j]);
    }
    ebh[kk] = uh.v; ebl[kk] = ul.v;
  }

  f32x4 acc[8];
  #pragma unroll
  for (int n=0;n<8;n++) acc[n] = (f32x4){0.f,0.f,0.f,0.f};

  #pragma unroll
  for (int kk=0;kk<4;kk++){
    #pragma unroll
    for (int n=0;n<8;n++){
      int wo = (n*16 + l15)*NH + kk*32 + lg*8;     // A row = h = n*16+l15
      union{ s16x8 s; bf16x8 v; } wh, wl;
      wh.s = *(const s16x8*)(Whi + wo);
      wl.s = *(const s16x8*)(Wlo + wo);
      acc[n] = __builtin_amdgcn_mfma_f32_16x16x32_bf16(wh.v, ebh[kk], acc[n], 0, 0, 0);
      acc[n] = __builtin_amdgcn_mfma_f32_16x16x32_bf16(wh.v, ebl[kk], acc[n], 0, 0, 0);
      acc[n] = __builtin_amdgcn_mfma_f32_16x16x32_bf16(wl.v, ebh[kk], acc[n], 0, 0, 0);
    }
  }

  // vector epilogue: lane owns edge e, h-chunks h0 = n*16 + lg*4 (+0..3)
  const float* bxr = bx + ((size_t)b*NV + sv)*NH;
  const float* cxr = cx + ((size_t)b*NV + dv)*NH;
  float* ehr = ehg + (size_t)e*NH;
  #pragma unroll
  for (int n=0;n<8;n++){
    int h0 = n*16 + lg*4;
    f32x4 ab4  = *(const f32x4*)(Ab  + h0);
    f32x4 bx4  = *(const f32x4*)(bxr + h0);
    f32x4 cx4  = *(const f32x4*)(cxr + h0);
    f32x4 old4 = *(const f32x4*)(ehr + h0);
    f32x4 nv;
    #pragma unroll
    for (int j=0;j<4;j++){
      float vv = acc[n][j] + ab4[j] + bx4[j] + cx4[j];
      vv = vv > 0.f ? vv : 0.f;
      nv[j] = old4[j] + vv;
    }
    *(f32x4*)(ehr + h0) = nv;
  }
}

// ---------------- node update: xh += relu(ux + agg0 + agg1) ----------------
__global__ __launch_bounds__(256) void k_node_update(
    float* __restrict__ xh, const float* __restrict__ ux, const float* __restrict__ agg)
{
  int i = blockIdx.x*256 + threadIdx.x;
  if (i >= NB*NV*NH) return;
  float u = ux[i] + agg[i] + agg[(size_t)NB*NV*NH + i];
  xh[i] += u > 0.f ? u : 0.f;
}

// ---------------- output: sigmoid(relu(eh@W1+b1)@W2+b2) ----------------
// same operand-swapped structure; takes BASE Wt (matrix 3 = hi, 7 = lo)
__global__ __launch_bounds__(256, 4) void k_out(
    const float* __restrict__ eh, const short* __restrict__ Wt,
    const float* __restrict__ b1, const float* __restrict__ W2,
    const float* __restrict__ b2, float* __restrict__ out)
{
  int tile = blockIdx.x % TILES;
  int b    = blockIdx.x / TILES;
  int wave = threadIdx.x >> 6;
  int lane = threadIdx.x & 63;
  int l15 = lane & 15, lg = lane >> 4;
  int e0 = tile*64 + wave*16;
  int e  = e0 + l15;
  const float* ehg = eh + (size_t)b*NE*NH;
  const short* Whi = Wt + 3*NH*NH;
  const short* Wlo = Wt + 7*NH*NH;

  const float* bptr = ehg + (size_t)e*NH + lg*8;
  bf16x8 ebh[4], ebl[4];
  #pragma unroll
  for (int kk=0;kk<4;kk++){
    f32x4 p0 = *(const f32x4*)(bptr + kk*32);
    f32x4 p1 = *(const f32x4*)(bptr + kk*32 + 4);
    union{ short s[8]; bf16x8 v; } uh, ul;
    #pragma unroll
    for (int j=0;j<4;j++){
      splitb(p0[j], uh.s[j],   ul.s[j]);
      splitb(p1[j], uh.s[4+j], ul.s[4+j]);
    }
    ebh[kk] = uh.v; ebl[kk] = ul.v;
  }

  f32x4 acc[8];
  #pragma unroll
  for (int n=0;n<8;n++) acc[n] = (f32x4){0.f,0.f,0.f,0.f};
  #pragma unroll
  for (int kk=0;kk<4;kk++){
    #pragma unroll
    for (int n=0;n<8;n++){
      int wo = (n*16 + l15)*NH + kk*32 + lg*8;
      union{ s16x8 s; bf16x8 v; } wh, wl;
      wh.s = *(const s16x8*)(Whi + wo);
      wl.s = *(const s16x8*)(Wlo + wo);
      acc[n] = __builtin_amdgcn_mfma_f32_16x16x32_bf16(wh.v, ebh[kk], acc[n], 0, 0, 0);
      acc[n] = __builtin_amdgcn_mfma_f32_16x16x32_bf16(wh.v, ebl[kk], acc[n], 0, 0, 0);
      acc[n] = __builtin_amdgcn_mfma_f32_16x16x32_bf16(wl.v, ebh[kk], acc[n], 0, 0, 0);
    }
  }

  float p0 = 0.f, p1 = 0.f;
  #pragma unroll
  for (int n=0;n<8;n++){
    int h0 = n*16 + lg*4;
    f32x4 b14 = *(const f32x4*)(b1 + h0);
    f32x4 wA  = *(const f32x4*)(W2 + h0*2);      // {w[h0][0],w[h0][1],w[h0+1][0],w[h0+1][1]}
    f32x4 wB  = *(const f32x4*)(W2 + h0*2 + 4);
    float hv0 = acc[n][0] + b14[0]; hv0 = hv0 > 0.f ? hv0 : 0.f;
    float hv1 = acc[n][1] + b14[1]; hv1 = hv1 > 0.f ? hv1 : 0.f;
    float hv2 = acc[n][2] + b14[2]; hv2 = hv2 > 0.f ? hv2 : 0.f;
    float hv3 = acc[n][3] + b14[3]; hv3 = hv3 > 0.f ? hv3 : 0.f;
    p0 += hv0*wA[0] + hv1*wA[2] + hv2*wB[0] + hv3*wB[2];
    p1 += hv0*wA[1] + hv1*wA[3] + hv2*wB[1] + hv3*wB[3];
  }
  // reduce over lg (lanes differing in bits 4,5)
  p0 += __shfl_xor(p0, 16, 64); p0 += __shfl_xor(p0, 32, 64);
  p1 += __shfl_xor(p1, 16, 64); p1 += __shfl_xor(p1, 32, 64);
  if (lg == 0){
    float2 r;
    r.x = sigmoidf_(p0 + b2[0]);
    r.y = sigmoidf_(p1 + b2[1]);
    *(float2*)(out + ((size_t)b*NE + e)*2) = r;
  }
}

extern "C" void kernel_launch(void* const* d_in, const int* in_sizes, int n_in,
                              void* d_out, int out_size, void* d_ws, size_t ws_size,
                              hipStream_t stream)
{
  const float* x   = (const float*)d_in[0];
  const float* e   = (const float*)d_in[1];
  const int*   ei  = (const int*)d_in[2];
  const float* nW  = (const float*)d_in[3];
  const float* nb  = (const float*)d_in[4];
  const float* eW  = (const float*)d_in[5];
  const float* eb  = (const float*)d_in[6];
  const float* UW  = (const float*)d_in[7];
  const float* Ub  = (const float*)d_in[8];
  const float* VW  = (const float*)d_in[9];
  const float* Vb  = (const float*)d_in[10];
  const float* AW  = (const float*)d_in[11];
  const float* Ab  = (const float*)d_in[12];
  const float* BW  = (const float*)d_in[13];
  const float* Bb  = (const float*)d_in[14];
  const float* CW  = (const float*)d_in[15];
  const float* Cb  = (const float*)d_in[16];
  const float* oW1 = (const float*)d_in[17];
  const float* ob1 = (const float*)d_in[18];
  const float* oW2 = (const float*)d_in[19];
  const float* ob2 = (const float*)d_in[20];
  float* out = (float*)d_out;

  char* ws = (char*)d_ws;
  size_t off = 0;
  auto alloc = [&](size_t bytes)->char*{
    char* p = ws + off;
    off += (bytes + 255) & ~(size_t)255;
    return p;
  };
  float* eh     = (float*)alloc((size_t)NB*NE*NH*4);
  float* xh     = (float*)alloc((size_t)NB*NV*NH*4);
  float* vx     = (float*)alloc((size_t)NB*NV*NH*4);
  float* bx     = (float*)alloc((size_t)NB*NV*NH*4);
  float* cx     = (float*)alloc((size_t)NB*NV*NH*4);
  float* ux     = (float*)alloc((size_t)NB*NV*NH*4);
  float* agg    = (float*)alloc((size_t)2*NB*NV*NH*4);
  short* Wt     = (short*)alloc((size_t)8*NH*NH*2);
  int* counts   = (int*)alloc((size_t)NB*NV*4);
  int* cursor   = (int*)alloc((size_t)NB*NV*4);
  int* offs     = (int*)alloc((size_t)NB*(NV+1)*4);
  int* csr      = (int*)alloc((size_t)NB*NE*4);
  (void)ws_size; (void)in_sizes; (void)n_in; (void)out_size;

  k_embed_nodes<<<(NB*NV*NH+255)/256, 256, 0, stream>>>(x, nW, nb, xh);
  k_embed_edges<<<(NB*NE*NH/4+255)/256, 256, 0, stream>>>(e, eW, eb, eh);
  k_trans_w<<<4, 256, 0, stream>>>(AW, oW1, Wt);
  k_zero<<<(NB*NV+255)/256, 256, 0, stream>>>(counts, NB*NV);
  k_count<<<(NB*NE+255)/256, 256, 0, stream>>>(ei, counts);
  k_scan<<<NB, 64, 0, stream>>>(counts, offs, cursor);
  k_scatter<<<(NB*NE+255)/256, 256, 0, stream>>>(ei, cursor, csr);

  for (int l=0; l<NL; l++){
    k_node_mm<<<NB*NV, 256, 0, stream>>>(xh,
        VW + l*NH*NH, Vb + l*NH, BW + l*NH*NH, Bb + l*NH,
        CW + l*NH*NH, Cb + l*NH, UW + l*NH*NH, Ub + l*NH,
        vx, bx, cx, ux);
    k_agg<<<NB*NV*2, 128, 0, stream>>>(eh, vx, ei, csr, offs, agg);
    k_edge_update<<<NB*TILES, 256, 0, stream>>>(eh, Wt + l*NH*NH, Ab + l*NH, bx, cx, ei);
    k_node_update<<<(NB*NV*NH+255)/256, 256, 0, stream>>>(xh, ux, agg);
  }
  k_out<<<NB*TILES, 256, 0, stream>>>(eh, Wt, ob1, oW2, ob2, out);
}

// Round 5
// 735.439 us; speedup vs baseline: 1.5448x; 1.5448x over previous
//
#include <hip/hip_runtime.h>
#include <hip/hip_bf16.h>

#define NB 8
#define NV 200
#define NE 40000
#define NH 128
#define NL 3
#define EBLK 313        // ceil(NE/128): 128 edges per block (4 waves x 2 tiles of 16)

typedef __attribute__((ext_vector_type(8))) __bf16 bf16x8;
typedef __attribute__((ext_vector_type(8))) short s16x8;
typedef __attribute__((ext_vector_type(4))) float f32x4;

__device__ inline float sigmoidf_(float x){ return 1.0f/(1.0f + __expf(-x)); }

// round-to-nearest-even f32 -> bf16 bits
__device__ inline short f2b(float f){
  union{ float f; unsigned u; } v; v.f = f;
  unsigned u = v.u;
  u += 0x7fffu + ((u >> 16) & 1u);
  return (short)(u >> 16);
}
__device__ inline float b2f(short s){
  union{ unsigned u; float f; } v; v.u = ((unsigned)(unsigned short)s) << 16;
  return v.f;
}
// split x ~= hi + lo, both bf16
__device__ inline void splitb(float x, short &hi, short &lo){
  hi = f2b(x);
  lo = f2b(x - b2f(hi));
}

// ---------------- embed ----------------
__global__ __launch_bounds__(256) void k_embed_nodes(
    const float* __restrict__ x, const float* __restrict__ nW,
    const float* __restrict__ nb, float* __restrict__ xh)
{
  int i = blockIdx.x*256 + threadIdx.x;
  if (i >= NB*NV*NH) return;
  int h  = i & (NH-1);
  int bv = i >> 7;
  xh[i] = x[bv*2+0]*nW[h] + x[bv*2+1]*nW[NH+h] + nb[h];
}

__global__ __launch_bounds__(256) void k_embed_edges(
    const float* __restrict__ e, const float* __restrict__ eW,
    const float* __restrict__ eb, float* __restrict__ eh)
{
  int i = blockIdx.x*256 + threadIdx.x;       // over NB*NE*NH/4
  if (i >= NB*NE*NH/4) return;
  int h4 = i & (NH/4 - 1);
  int be = i >> 5;
  float ev = e[be];
  f32x4 w  = *(const f32x4*)(eW + h4*4);
  f32x4 bb = *(const f32x4*)(eb + h4*4);
  f32x4 r;
  #pragma unroll
  for (int j=0;j<4;j++) r[j] = ev*w[j] + bb[j];
  *(f32x4*)(eh + (size_t)be*NH + h4*4) = r;
}

// ---------------- weight transpose to split bf16 (Wt[n][k] = W[k][n]) ----------------
// layout: Wt + m*NH*NH        -> hi of matrix m   (m = 0..2: A_W layers, 3: out_W1)
//         Wt + (4+m)*NH*NH    -> lo of matrix m
__global__ __launch_bounds__(256) void k_trans_w(
    const float* __restrict__ AW, const float* __restrict__ oW1,
    short* __restrict__ Wt)
{
  int m = blockIdx.x;                         // 0..3
  const float* src = (m < 3) ? (AW + m*NH*NH) : oW1;
  short* dhi = Wt + (size_t)m*NH*NH;
  short* dlo = Wt + (size_t)(4+m)*NH*NH;
  for (int i = threadIdx.x; i < NH*NH; i += 256){
    int n = i >> 7, k = i & 127;
    short hi, lo;
    splitb(src[k*NH + n], hi, lo);
    dhi[i] = hi; dlo[i] = lo;
  }
}

// ---------------- CSR build ----------------
__global__ __launch_bounds__(256) void k_zero(int* __restrict__ p, int n){
  int i = blockIdx.x*256 + threadIdx.x;
  if (i < n) p[i] = 0;
}

__global__ __launch_bounds__(256) void k_count(const int* __restrict__ ei, int* __restrict__ counts){
  int i = blockIdx.x*256 + threadIdx.x;
  if (i >= NB*NE) return;
  int b = i / NE, e = i % NE;
  int dv = ei[b*2*NE + NE + e];
  atomicAdd(&counts[b*NV + dv], 1);
}

__global__ void k_scan(const int* __restrict__ counts, int* __restrict__ offs, int* __restrict__ cursor){
  int b = blockIdx.x;
  if (threadIdx.x == 0){
    int run = 0;
    for (int v=0; v<NV; v++){
      offs[b*(NV+1)+v] = run;
      cursor[b*NV+v]   = run;
      run += counts[b*NV+v];
    }
    offs[b*(NV+1)+NV] = run;
  }
}

__global__ __launch_bounds__(256) void k_scatter(const int* __restrict__ ei, int* __restrict__ cursor, int* __restrict__ csr){
  int i = blockIdx.x*256 + threadIdx.x;
  if (i >= NB*NE) return;
  int b = i / NE, e = i % NE;
  int dv = ei[b*2*NE + NE + e];
  int pos = atomicAdd(&cursor[b*NV + dv], 1);
  csr[(size_t)b*NE + pos] = e;
}

// ---------------- per-layer node matmuls: vx,bx,cx,ux ----------------
__global__ __launch_bounds__(256) void k_node_mm(
    const float* __restrict__ xh,
    const float* __restrict__ VWl, const float* __restrict__ Vbl,
    const float* __restrict__ BWl, const float* __restrict__ Bbl,
    const float* __restrict__ CWl, const float* __restrict__ Cbl,
    const float* __restrict__ UWl, const float* __restrict__ Ubl,
    float* __restrict__ vx, float* __restrict__ bx,
    float* __restrict__ cx, float* __restrict__ ux)
{
  __shared__ float sx[NH];
  int b = blockIdx.x / NV, v = blockIdx.x % NV;
  const float* xr = xh + ((size_t)b*NV + v)*NH;
  if (threadIdx.x < NH) sx[threadIdx.x] = xr[threadIdx.x];
  __syncthreads();
  #pragma unroll
  for (int pass=0; pass<2; pass++){
    int t = threadIdx.x + pass*256;
    int mat = t >> 7, h = t & 127;
    const float* W = (mat==0) ? VWl : (mat==1) ? BWl : (mat==2) ? CWl : UWl;
    const float* bs = (mat==0) ? Vbl : (mat==1) ? Bbl : (mat==2) ? Cbl : Ubl;
    float* op = (mat==0) ? vx : (mat==1) ? bx : (mat==2) ? cx : ux;
    float acc = bs[h];
    #pragma unroll 8
    for (int k=0;k<NH;k++) acc += sx[k]*W[k*NH + h];
    op[((size_t)b*NV + v)*NH + h] = acc;
  }
}

// ---------------- aggregation (2 partial blocks per node) ----------------
__global__ __launch_bounds__(128) void k_agg(
    const float* __restrict__ eh, const float* __restrict__ vx,
    const int* __restrict__ ei, const int* __restrict__ csr,
    const int* __restrict__ offs, float* __restrict__ agg)
{
  int part = blockIdx.x & 1;
  int bv   = blockIdx.x >> 1;
  int b = bv / NV, v = bv % NV;
  int h = threadIdx.x;
  const int* srcp  = ei + b*2*NE;
  const int* csrg  = csr + (size_t)b*NE;
  const float* ehg = eh + (size_t)b*NE*NH;
  const float* vxg = vx + (size_t)b*NV*NH;
  int beg = offs[b*(NV+1)+v], end = offs[b*(NV+1)+v+1];
  int mid = (beg + end) >> 1;
  int i    = part ? mid : beg;
  int stop = part ? end : mid;
  float acc = 0.f;
  for (; i+8 <= stop; i += 8){
    int   eb[8], sb[8];
    float a[8], w[8];
    #pragma unroll
    for (int j=0;j<8;j++) eb[j] = csrg[i+j];
    #pragma unroll
    for (int j=0;j<8;j++) sb[j] = srcp[eb[j]];
    #pragma unroll
    for (int j=0;j<8;j++) a[j] = ehg[(size_t)eb[j]*NH + h];
    #pragma unroll
    for (int j=0;j<8;j++) w[j] = vxg[sb[j]*NH + h];
    #pragma unroll
    for (int j=0;j<8;j++) acc += sigmoidf_(a[j]) * w[j];
  }
  for (; i < stop; i++){
    int e0 = csrg[i]; int s0 = srcp[e0];
    acc += sigmoidf_(ehg[(size_t)e0*NH+h]) * vxg[s0*NH+h];
  }
  agg[((size_t)part*NB*NV + (size_t)b*NV + v)*NH + h] = acc;
}

// ---------------- edge update: eh += relu(eh@A_W + A_b + bx[src] + cx[dst]) ----------------
// A = W (rows = h), B = eh^T (cols = edges). W_hi staged in LDS (XOR-swizzled),
// W_lo from global (L2). Each wave: 2 edge-tiles (32 edges), all eh frag loads
// issued up front for MLP.
__global__ __launch_bounds__(256) void k_edge_update(
    float* __restrict__ eh, const short* __restrict__ Wt,
    const float* __restrict__ Ab, const float* __restrict__ bx,
    const float* __restrict__ cx, const int* __restrict__ ei)
{
  __shared__ short sW[NH*NH];           // 32 KB, swizzled W_hi
  const short* Whi = Wt;
  const short* Wlo = Wt + 4*NH*NH;

  // stage W_hi -> LDS (swizzle: short-idx k ^= (h&7)<<3; same XOR on read)
  {
    int t = threadIdx.x;
    #pragma unroll
    for (int i=0;i<8;i++){
      int sidx = (t + i*256)*8;               // short index, 8 shorts per store
      int h  = sidx >> 7;
      int kw = sidx & 127;
      s16x8 v = *(const s16x8*)(Whi + sidx);
      *(s16x8*)(sW + h*128 + (kw ^ ((h&7)<<3))) = v;
    }
  }
  __syncthreads();

  int blk  = blockIdx.x % EBLK;
  int b    = blockIdx.x / EBLK;
  int wave = threadIdx.x >> 6;
  int lane = threadIdx.x & 63;
  int l15 = lane & 15, lg = lane >> 4;
  int eA = blk*128 + wave*32 + l15;     // tile 0
  int eB = eA + 16;                     // tile 1
  int eAc = eA < NE ? eA : NE-1;
  int eBc = eB < NE ? eB : NE-1;
  float* ehg = eh + (size_t)b*NE*NH;
  const int* srcp = ei + b*2*NE;
  int svA = srcp[eAc], dvA = srcp[NE+eAc];
  int svB = srcp[eBc], dvB = srcp[NE+eBc];

  // all eh fragment loads first (max in-flight HBM bytes)
  const float* pA = ehg + (size_t)eAc*NH + lg*8;
  const float* pB = ehg + (size_t)eBc*NH + lg*8;
  f32x4 rA[8], rB[8];
  #pragma unroll
  for (int kk=0;kk<4;kk++){
    rA[2*kk]   = *(const f32x4*)(pA + kk*32);
    rA[2*kk+1] = *(const f32x4*)(pA + kk*32 + 4);
  }
  #pragma unroll
  for (int kk=0;kk<4;kk++){
    rB[2*kk]   = *(const f32x4*)(pB + kk*32);
    rB[2*kk+1] = *(const f32x4*)(pB + kk*32 + 4);
  }

  bf16x8 ahA[4], alA[4], ahB[4], alB[4];
  #pragma unroll
  for (int kk=0;kk<4;kk++){
    union{ short s[8]; bf16x8 v; } uh, ul;
    #pragma unroll
    for (int j=0;j<4;j++){
      splitb(rA[2*kk][j],   uh.s[j],   ul.s[j]);
      splitb(rA[2*kk+1][j], uh.s[4+j], ul.s[4+j]);
    }
    ahA[kk] = uh.v; alA[kk] = ul.v;
  }
  #pragma unroll
  for (int kk=0;kk<4;kk++){
    union{ short s[8]; bf16x8 v; } uh, ul;
    #pragma unroll
    for (int j=0;j<4;j++){
      splitb(rB[2*kk][j],   uh.s[j],   ul.s[j]);
      splitb(rB[2*kk+1][j], uh.s[4+j], ul.s[4+j]);
    }
    ahB[kk] = uh.v; alB[kk] = ul.v;
  }

  f32x4 accA[8], accB[8];
  #pragma unroll
  for (int n=0;n<8;n++){ accA[n] = (f32x4){0.f,0.f,0.f,0.f}; accB[n] = (f32x4){0.f,0.f,0.f,0.f}; }

  #pragma unroll
  for (int kk=0;kk<4;kk++){
    #pragma unroll
    for (int n=0;n<8;n++){
      int row = n*16 + l15;
      union{ s16x8 s; bf16x8 v; } wh, wl;
      wh.s = *(const s16x8*)(sW + row*128 + ((kk*32 + lg*8) ^ ((l15&7)<<3)));
      wl.s = *(const s16x8*)(Wlo + row*NH + kk*32 + lg*8);
      accA[n] = __builtin_amdgcn_mfma_f32_16x16x32_bf16(wh.v, ahA[kk], accA[n], 0, 0, 0);
      accA[n] = __builtin_amdgcn_mfma_f32_16x16x32_bf16(wh.v, alA[kk], accA[n], 0, 0, 0);
      accA[n] = __builtin_amdgcn_mfma_f32_16x16x32_bf16(wl.v, ahA[kk], accA[n], 0, 0, 0);
      accB[n] = __builtin_amdgcn_mfma_f32_16x16x32_bf16(wh.v, ahB[kk], accB[n], 0, 0, 0);
      accB[n] = __builtin_amdgcn_mfma_f32_16x16x32_bf16(wh.v, alB[kk], accB[n], 0, 0, 0);
      accB[n] = __builtin_amdgcn_mfma_f32_16x16x32_bf16(wl.v, ahB[kk], accB[n], 0, 0, 0);
    }
  }

  // vector epilogue: C row = lg*4+reg -> h = n*16+lg*4+reg, col = l15 -> edge
  const float* bxA = bx + ((size_t)b*NV + svA)*NH;
  const float* cxA = cx + ((size_t)b*NV + dvA)*NH;
  const float* bxB = bx + ((size_t)b*NV + svB)*NH;
  const float* cxB = cx + ((size_t)b*NV + dvB)*NH;
  float* ehA = ehg + (size_t)eAc*NH;
  float* ehB = ehg + (size_t)eBc*NH;
  #pragma unroll
  for (int n=0;n<8;n++){
    int h0 = n*16 + lg*4;
    f32x4 ab4 = *(const f32x4*)(Ab + h0);
    f32x4 bA = *(const f32x4*)(bxA + h0);
    f32x4 cA = *(const f32x4*)(cxA + h0);
    f32x4 oA = *(const f32x4*)(ehA + h0);
    f32x4 bB = *(const f32x4*)(bxB + h0);
    f32x4 cB = *(const f32x4*)(cxB + h0);
    f32x4 oB = *(const f32x4*)(ehB + h0);
    f32x4 nA, nB;
    #pragma unroll
    for (int j=0;j<4;j++){
      float vA = accA[n][j] + ab4[j] + bA[j] + cA[j];
      vA = vA > 0.f ? vA : 0.f;
      nA[j] = oA[j] + vA;
      float vB = accB[n][j] + ab4[j] + bB[j] + cB[j];
      vB = vB > 0.f ? vB : 0.f;
      nB[j] = oB[j] + vB;
    }
    if (eA < NE) *(f32x4*)(ehA + h0) = nA;
    if (eB < NE) *(f32x4*)(ehB + h0) = nB;
  }
}

// ---------------- node update: xh += relu(ux + agg0 + agg1) ----------------
__global__ __launch_bounds__(256) void k_node_update(
    float* __restrict__ xh, const float* __restrict__ ux, const float* __restrict__ agg)
{
  int i = blockIdx.x*256 + threadIdx.x;
  if (i >= NB*NV*NH) return;
  float u = ux[i] + agg[i] + agg[(size_t)NB*NV*NH + i];
  xh[i] += u > 0.f ? u : 0.f;
}

// ---------------- output: sigmoid(relu(eh@W1+b1)@W2+b2) ----------------
// same structure as k_edge_update; W1_hi in LDS, W1_lo global.
__global__ __launch_bounds__(256) void k_out(
    const float* __restrict__ eh, const short* __restrict__ Wt,
    const float* __restrict__ b1, const float* __restrict__ W2,
    const float* __restrict__ b2, float* __restrict__ out)
{
  __shared__ short sW[NH*NH];
  const short* Whi = Wt + 3*NH*NH;
  const short* Wlo = Wt + 7*NH*NH;
  {
    int t = threadIdx.x;
    #pragma unroll
    for (int i=0;i<8;i++){
      int sidx = (t + i*256)*8;
      int h  = sidx >> 7;
      int kw = sidx & 127;
      s16x8 v = *(const s16x8*)(Whi + sidx);
      *(s16x8*)(sW + h*128 + (kw ^ ((h&7)<<3))) = v;
    }
  }
  __syncthreads();

  int blk  = blockIdx.x % EBLK;
  int b    = blockIdx.x / EBLK;
  int wave = threadIdx.x >> 6;
  int lane = threadIdx.x & 63;
  int l15 = lane & 15, lg = lane >> 4;
  int eA = blk*128 + wave*32 + l15;
  int eB = eA + 16;
  int eAc = eA < NE ? eA : NE-1;
  int eBc = eB < NE ? eB : NE-1;
  const float* ehg = eh + (size_t)b*NE*NH;

  const float* pA = ehg + (size_t)eAc*NH + lg*8;
  const float* pB = ehg + (size_t)eBc*NH + lg*8;
  f32x4 rA[8], rB[8];
  #pragma unroll
  for (int kk=0;kk<4;kk++){
    rA[2*kk]   = *(const f32x4*)(pA + kk*32);
    rA[2*kk+1] = *(const f32x4*)(pA + kk*32 + 4);
  }
  #pragma unroll
  for (int kk=0;kk<4;kk++){
    rB[2*kk]   = *(const f32x4*)(pB + kk*32);
    rB[2*kk+1] = *(const f32x4*)(pB + kk*32 + 4);
  }

  bf16x8 ahA[4], alA[4], ahB[4], alB[4];
  #pragma unroll
  for (int kk=0;kk<4;kk++){
    union{ short s[8]; bf16x8 v; } uh, ul;
    #pragma unroll
    for (int j=0;j<4;j++){
      splitb(rA[2*kk][j],   uh.s[j],   ul.s[j]);
      splitb(rA[2*kk+1][j], uh.s[4+j], ul.s[4+j]);
    }
    ahA[kk] = uh.v; alA[kk] = ul.v;
  }
  #pragma unroll
  for (int kk=0;kk<4;kk++){
    union{ short s[8]; bf16x8 v; } uh, ul;
    #pragma unroll
    for (int j=0;j<4;j++){
      splitb(rB[2*kk][j],   uh.s[j],   ul.s[j]);
      splitb(rB[2*kk+1][j], uh.s[4+j], ul.s[4+j]);
    }
    ahB[kk] = uh.v; alB[kk] = ul.v;
  }

  f32x4 accA[8], accB[8];
  #pragma unroll
  for (int n=0;n<8;n++){ accA[n] = (f32x4){0.f,0.f,0.f,0.f}; accB[n] = (f32x4){0.f,0.f,0.f,0.f}; }
  #pragma unroll
  for (int kk=0;kk<4;kk++){
    #pragma unroll
    for (int n=0;n<8;n++){
      int row = n*16 + l15;
      union{ s16x8 s; bf16x8 v; } wh, wl;
      wh.s = *(const s16x8*)(sW + row*128 + ((kk*32 + lg*8) ^ ((l15&7)<<3)));
      wl.s = *(const s16x8*)(Wlo + row*NH + kk*32 + lg*8);
      accA[n] = __builtin_amdgcn_mfma_f32_16x16x32_bf16(wh.v, ahA[kk], accA[n], 0, 0, 0);
      accA[n] = __builtin_amdgcn_mfma_f32_16x16x32_bf16(wh.v, alA[kk], accA[n], 0, 0, 0);
      accA[n] = __builtin_amdgcn_mfma_f32_16x16x32_bf16(wl.v, ahA[kk], accA[n], 0, 0, 0);
      accB[n] = __builtin_amdgcn_mfma_f32_16x16x32_bf16(wh.v, ahB[kk], accB[n], 0, 0, 0);
      accB[n] = __builtin_amdgcn_mfma_f32_16x16x32_bf16(wh.v, alB[kk], accB[n], 0, 0, 0);
      accB[n] = __builtin_amdgcn_mfma_f32_16x16x32_bf16(wl.v, ahB[kk], accB[n], 0, 0, 0);
    }
  }

  float p0A = 0.f, p1A = 0.f, p0B = 0.f, p1B = 0.f;
  #pragma unroll
  for (int n=0;n<8;n++){
    int h0 = n*16 + lg*4;
    f32x4 b14 = *(const f32x4*)(b1 + h0);
    f32x4 wA  = *(const f32x4*)(W2 + h0*2);
    f32x4 wB  = *(const f32x4*)(W2 + h0*2 + 4);
    #pragma unroll
    for (int j=0;j<4;j++){
      float w20 = (j<2) ? wA[2*j]   : wB[2*(j-2)];
      float w21 = (j<2) ? wA[2*j+1] : wB[2*(j-2)+1];
      float hA = accA[n][j] + b14[j]; hA = hA > 0.f ? hA : 0.f;
      float hB = accB[n][j] + b14[j]; hB = hB > 0.f ? hB : 0.f;
      p0A += hA*w20; p1A += hA*w21;
      p0B += hB*w20; p1B += hB*w21;
    }
  }
  p0A += __shfl_xor(p0A, 16, 64); p0A += __shfl_xor(p0A, 32, 64);
  p1A += __shfl_xor(p1A, 16, 64); p1A += __shfl_xor(p1A, 32, 64);
  p0B += __shfl_xor(p0B, 16, 64); p0B += __shfl_xor(p0B, 32, 64);
  p1B += __shfl_xor(p1B, 16, 64); p1B += __shfl_xor(p1B, 32, 64);
  if (lg == 0){
    float bb0 = b2[0], bb1 = b2[1];
    if (eA < NE){
      float2 r; r.x = sigmoidf_(p0A + bb0); r.y = sigmoidf_(p1A + bb1);
      *(float2*)(out + ((size_t)b*NE + eA)*2) = r;
    }
    if (eB < NE){
      float2 r; r.x = sigmoidf_(p0B + bb0); r.y = sigmoidf_(p1B + bb1);
      *(float2*)(out + ((size_t)b*NE + eB)*2) = r;
    }
  }
}

extern "C" void kernel_launch(void* const* d_in, const int* in_sizes, int n_in,
                              void* d_out, int out_size, void* d_ws, size_t ws_size,
                              hipStream_t stream)
{
  const float* x   = (const float*)d_in[0];
  const float* e   = (const float*)d_in[1];
  const int*   ei  = (const int*)d_in[2];
  const float* nW  = (const float*)d_in[3];
  const float* nb  = (const float*)d_in[4];
  const float* eW  = (const float*)d_in[5];
  const float* eb  = (const float*)d_in[6];
  const float* UW  = (const float*)d_in[7];
  const float* Ub  = (const float*)d_in[8];
  const float* VW  = (const float*)d_in[9];
  const float* Vb  = (const float*)d_in[10];
  const float* AW  = (const float*)d_in[11];
  const float* Ab  = (const float*)d_in[12];
  const float* BW  = (const float*)d_in[13];
  const float* Bb  = (const float*)d_in[14];
  const float* CW  = (const float*)d_in[15];
  const float* Cb  = (const float*)d_in[16];
  const float* oW1 = (const float*)d_in[17];
  const float* ob1 = (const float*)d_in[18];
  const float* oW2 = (const float*)d_in[19];
  const float* ob2 = (const float*)d_in[20];
  float* out = (float*)d_out;

  char* ws = (char*)d_ws;
  size_t off = 0;
  auto alloc = [&](size_t bytes)->char*{
    char* p = ws + off;
    off += (bytes + 255) & ~(size_t)255;
    return p;
  };
  float* eh     = (float*)alloc((size_t)NB*NE*NH*4);
  float* xh     = (float*)alloc((size_t)NB*NV*NH*4);
  float* vx     = (float*)alloc((size_t)NB*NV*NH*4);
  float* bx     = (float*)alloc((size_t)NB*NV*NH*4);
  float* cx     = (float*)alloc((size_t)NB*NV*NH*4);
  float* ux     = (float*)alloc((size_t)NB*NV*NH*4);
  float* agg    = (float*)alloc((size_t)2*NB*NV*NH*4);
  short* Wt     = (short*)alloc((size_t)8*NH*NH*2);
  int* counts   = (int*)alloc((size_t)NB*NV*4);
  int* cursor   = (int*)alloc((size_t)NB*NV*4);
  int* offs     = (int*)alloc((size_t)NB*(NV+1)*4);
  int* csr      = (int*)alloc((size_t)NB*NE*4);
  (void)ws_size; (void)in_sizes; (void)n_in; (void)out_size;

  k_embed_nodes<<<(NB*NV*NH+255)/256, 256, 0, stream>>>(x, nW, nb, xh);
  k_embed_edges<<<(NB*NE*NH/4+255)/256, 256, 0, stream>>>(e, eW, eb, eh);
  k_trans_w<<<4, 256, 0, stream>>>(AW, oW1, Wt);
  k_zero<<<(NB*NV+255)/256, 256, 0, stream>>>(counts, NB*NV);
  k_count<<<(NB*NE+255)/256, 256, 0, stream>>>(ei, counts);
  k_scan<<<NB, 64, 0, stream>>>(counts, offs, cursor);
  k_scatter<<<(NB*NE+255)/256, 256, 0, stream>>>(ei, cursor, csr);

  for (int l=0; l<NL; l++){
    k_node_mm<<<NB*NV, 256, 0, stream>>>(xh,
        VW + l*NH*NH, Vb + l*NH, BW + l*NH*NH, Bb + l*NH,
        CW + l*NH*NH, Cb + l*NH, UW + l*NH*NH, Ub + l*NH,
        vx, bx, cx, ux);
    k_agg<<<NB*NV*2, 128, 0, stream>>>(eh, vx, ei, csr, offs, agg);
    k_edge_update<<<NB*EBLK, 256, 0, stream>>>(eh, Wt + l*NH*NH, Ab + l*NH, bx, cx, ei);
    k_node_update<<<(NB*NV*NH+255)/256, 256, 0, stream>>>(xh, ux, agg);
  }
  k_out<<<NB*EBLK, 256, 0, stream>>>(eh, Wt, ob1, oW2, ob2, out);
}

// Round 6
// 554.935 us; speedup vs baseline: 2.0473x; 1.3253x over previous
//
#include <hip/hip_runtime.h>
#include <hip/hip_bf16.h>

#define NB 8
#define NV 200
#define NE 40000
#define NH 128
#define NL 3
#define EBLK 313        // ceil(NE/128): 128 edges per block (4 waves x 2 tiles of 16)

typedef __attribute__((ext_vector_type(8))) __bf16 bf16x8;
typedef __attribute__((ext_vector_type(8))) short s16x8;
typedef __attribute__((ext_vector_type(4))) float f32x4;

__device__ inline float sigmoidf_(float x){ return 1.0f/(1.0f + __expf(-x)); }

// round-to-nearest-even f32 -> bf16 bits
__device__ inline short f2b(float f){
  union{ float f; unsigned u; } v; v.f = f;
  unsigned u = v.u;
  u += 0x7fffu + ((u >> 16) & 1u);
  return (short)(u >> 16);
}
__device__ inline float b2f(short s){
  union{ unsigned u; float f; } v; v.u = ((unsigned)(unsigned short)s) << 16;
  return v.f;
}
__device__ inline void splitb(float x, short &hi, short &lo){
  hi = f2b(x);
  lo = f2b(x - b2f(hi));
}

// ---------------- embed nodes ----------------
__global__ __launch_bounds__(256) void k_embed_nodes(
    const float* __restrict__ x, const float* __restrict__ nW,
    const float* __restrict__ nb, float* __restrict__ xh)
{
  int i = blockIdx.x*256 + threadIdx.x;
  if (i >= NB*NV*NH) return;
  int h  = i & (NH-1);
  int bv = i >> 7;
  xh[i] = x[bv*2+0]*nW[h] + x[bv*2+1]*nW[NH+h] + nb[h];
}

// ---------------- weight transpose to split bf16 (Wt[n][k] = W[k][n]) ----------------
// Wt + m*NH*NH -> hi of matrix m (0..2: A_W, 3: out_W1); Wt + (4+m)*NH*NH -> lo
__global__ __launch_bounds__(256) void k_trans_w(
    const float* __restrict__ AW, const float* __restrict__ oW1,
    short* __restrict__ Wt)
{
  int m = blockIdx.x;                         // 0..3
  const float* src = (m < 3) ? (AW + m*NH*NH) : oW1;
  short* dhi = Wt + (size_t)m*NH*NH;
  short* dlo = Wt + (size_t)(4+m)*NH*NH;
  for (int i = threadIdx.x; i < NH*NH; i += 256){
    int n = i >> 7, k = i & 127;
    short hi, lo;
    splitb(src[k*NH + n], hi, lo);
    dhi[i] = hi; dlo[i] = lo;
  }
}

// ---------------- CSR build ----------------
__global__ __launch_bounds__(256) void k_zero(int* __restrict__ p, int n){
  int i = blockIdx.x*256 + threadIdx.x;
  if (i < n) p[i] = 0;
}

__global__ __launch_bounds__(256) void k_count(const int* __restrict__ ei, int* __restrict__ counts){
  int i = blockIdx.x*256 + threadIdx.x;
  if (i >= NB*NE) return;
  int b = i / NE, e = i % NE;
  int dv = ei[b*2*NE + NE + e];
  atomicAdd(&counts[b*NV + dv], 1);
}

__global__ void k_scan(const int* __restrict__ counts, int* __restrict__ offs, int* __restrict__ cursor){
  int b = blockIdx.x;
  if (threadIdx.x == 0){
    int run = 0;
    for (int v=0; v<NV; v++){
      offs[b*(NV+1)+v] = run;
      cursor[b*NV+v]   = run;
      run += counts[b*NV+v];
    }
    offs[b*(NV+1)+NV] = run;
  }
}

__global__ __launch_bounds__(256) void k_scatter(const int* __restrict__ ei, int* __restrict__ cursor, int* __restrict__ csr){
  int i = blockIdx.x*256 + threadIdx.x;
  if (i >= NB*NE) return;
  int b = i / NE, e = i % NE;
  int dv = ei[b*2*NE + NE + e];
  int pos = atomicAdd(&cursor[b*NV + dv], 1);
  csr[(size_t)b*NE + pos] = e;
}

// ---------------- node: (optional xh update from prev layer) + 4 matmuls ----------------
__global__ __launch_bounds__(256) void k_node_mm(
    float* __restrict__ xh, const float* __restrict__ agg,
    const float* __restrict__ VWl, const float* __restrict__ Vbl,
    const float* __restrict__ BWl, const float* __restrict__ Bbl,
    const float* __restrict__ CWl, const float* __restrict__ Cbl,
    const float* __restrict__ UWl, const float* __restrict__ Ubl,
    float* __restrict__ vx, float* __restrict__ bx,
    float* __restrict__ cx, float* __restrict__ ux,
    int do_update)
{
  __shared__ float sx[NH];
  int b = blockIdx.x / NV, v = blockIdx.x % NV;
  size_t row = (size_t)b*NV + v;
  float* xr = xh + row*NH;
  int ht = threadIdx.x;
  if (ht < NH){
    float xv = xr[ht];
    if (do_update){
      // xh += relu(ux_prev + agg0_prev + agg1_prev)  (reads happen BEFORE barrier;
      // ux is rewritten by this kernel only AFTER the barrier)
      float u = ux[row*NH + ht] + agg[row*NH + ht] + agg[(size_t)NB*NV*NH + row*NH + ht];
      xv += u > 0.f ? u : 0.f;
      xr[ht] = xv;
    }
    sx[ht] = xv;
  }
  __syncthreads();
  #pragma unroll
  for (int pass=0; pass<2; pass++){
    int t = threadIdx.x + pass*256;
    int mat = t >> 7, h = t & 127;
    const float* W = (mat==0) ? VWl : (mat==1) ? BWl : (mat==2) ? CWl : UWl;
    const float* bs = (mat==0) ? Vbl : (mat==1) ? Bbl : (mat==2) ? Cbl : Ubl;
    float* op = (mat==0) ? vx : (mat==1) ? bx : (mat==2) ? cx : ux;
    float acc = bs[h];
    #pragma unroll 8
    for (int k=0;k<NH;k++) acc += sx[k]*W[k*NH + h];
    op[row*NH + h] = acc;
  }
}

// ---------------- aggregation (2 partial blocks per node) ----------------
// l==0: gate computed on the fly from rank-1 embed (4B/edge instead of 512B/edge)
__global__ __launch_bounds__(128) void k_agg(
    const float* __restrict__ eh, const float* __restrict__ evec,
    const float* __restrict__ eWe, const float* __restrict__ ebe,
    const float* __restrict__ vx, const int* __restrict__ ei,
    const int* __restrict__ csr, const int* __restrict__ offs,
    float* __restrict__ agg, int is_l0)
{
  int part = blockIdx.x & 1;
  int bv   = blockIdx.x >> 1;
  int b = bv / NV, v = bv % NV;
  int h = threadIdx.x;
  const int* srcp  = ei + b*2*NE;
  const int* csrg  = csr + (size_t)b*NE;
  const float* ehg = eh + (size_t)b*NE*NH;
  const float* evg = evec + (size_t)b*NE;
  const float* vxg = vx + (size_t)b*NV*NH;
  float wh = eWe[h], bh = ebe[h];
  int beg = offs[b*(NV+1)+v], end = offs[b*(NV+1)+v+1];
  int mid = (beg + end) >> 1;
  int i    = part ? mid : beg;
  int stop = part ? end : mid;
  float acc = 0.f;
  for (; i+8 <= stop; i += 8){
    int   eb[8], sb[8];
    float a[8], w[8];
    #pragma unroll
    for (int j=0;j<8;j++) eb[j] = csrg[i+j];
    #pragma unroll
    for (int j=0;j<8;j++) sb[j] = srcp[eb[j]];
    if (is_l0){
      #pragma unroll
      for (int j=0;j<8;j++) a[j] = evg[eb[j]]*wh + bh;
    } else {
      #pragma unroll
      for (int j=0;j<8;j++) a[j] = ehg[(size_t)eb[j]*NH + h];
    }
    #pragma unroll
    for (int j=0;j<8;j++) w[j] = vxg[sb[j]*NH + h];
    #pragma unroll
    for (int j=0;j<8;j++) acc += sigmoidf_(a[j]) * w[j];
  }
  for (; i < stop; i++){
    int e0 = csrg[i]; int s0 = srcp[e0];
    float a = is_l0 ? (evg[e0]*wh + bh) : ehg[(size_t)e0*NH+h];
    acc += sigmoidf_(a) * vxg[s0*NH+h];
  }
  agg[((size_t)part*NB*NV + (size_t)b*NV + v)*NH + h] = acc;
}

// ---------------- edge update: eh_new = eh_old + relu(eh_old@A_W + A_b + bx[src] + cx[dst]) --------
// W_hi AND W_lo staged in LDS (64KB, XOR-swizzled) -> MFMA loop has zero global latency.
// l==0: eh_old = ev*eW+eb computed on the fly (rank-1), no eh read at all.
__global__ __launch_bounds__(256) void k_edge_update(
    float* __restrict__ eh, const short* __restrict__ Wt,
    const float* __restrict__ Ab, const float* __restrict__ bx,
    const float* __restrict__ cx, const int* __restrict__ ei,
    const float* __restrict__ evec, const float* __restrict__ eWe,
    const float* __restrict__ ebe, int is_l0)
{
  __shared__ short sW[2*NH*NH];         // 64 KB: [0..16383]=hi, [16384..]=lo
  const short* Whi = Wt;
  const short* Wlo = Wt + 4*NH*NH;
  {
    #pragma unroll
    for (int i=0;i<16;i++){
      int sidx = (threadIdx.x + i*256)*8;       // short index 0..32767
      int p = sidx >> 14, r = sidx & 16383;
      int hh = r >> 7, kw = r & 127;
      const short* src = p ? Wlo : Whi;
      s16x8 vv = *(const s16x8*)(src + r);
      *(s16x8*)(sW + p*16384 + hh*128 + (kw ^ ((hh&7)<<3))) = vv;
    }
  }
  __syncthreads();

  int blk  = blockIdx.x % EBLK;
  int b    = blockIdx.x / EBLK;
  int wave = threadIdx.x >> 6;
  int lane = threadIdx.x & 63;
  int l15 = lane & 15, lg = lane >> 4;
  int eA = blk*128 + wave*32 + l15;
  int eB = eA + 16;
  int eAc = eA < NE ? eA : NE-1;
  int eBc = eB < NE ? eB : NE-1;
  float* ehg = eh + (size_t)b*NE*NH;
  const int* srcp = ei + b*2*NE;
  int svA = srcp[eAc], dvA = srcp[NE+eAc];
  int svB = srcp[eBc], dvB = srcp[NE+eBc];

  float evA = 0.f, evB = 0.f;
  f32x4 rA[8], rB[8];
  if (is_l0){
    evA = evec[(size_t)b*NE + eAc];
    evB = evec[(size_t)b*NE + eBc];
    #pragma unroll
    for (int kk=0;kk<4;kk++){
      f32x4 w0 = *(const f32x4*)(eWe + kk*32 + lg*8);
      f32x4 w1 = *(const f32x4*)(eWe + kk*32 + lg*8 + 4);
      f32x4 q0 = *(const f32x4*)(ebe + kk*32 + lg*8);
      f32x4 q1 = *(const f32x4*)(ebe + kk*32 + lg*8 + 4);
      #pragma unroll
      for (int j=0;j<4;j++){
        rA[2*kk][j]   = evA*w0[j] + q0[j];
        rA[2*kk+1][j] = evA*w1[j] + q1[j];
        rB[2*kk][j]   = evB*w0[j] + q0[j];
        rB[2*kk+1][j] = evB*w1[j] + q1[j];
      }
    }
  } else {
    const float* pA = ehg + (size_t)eAc*NH + lg*8;
    const float* pB = ehg + (size_t)eBc*NH + lg*8;
    #pragma unroll
    for (int kk=0;kk<4;kk++){
      rA[2*kk]   = *(const f32x4*)(pA + kk*32);
      rA[2*kk+1] = *(const f32x4*)(pA + kk*32 + 4);
    }
    #pragma unroll
    for (int kk=0;kk<4;kk++){
      rB[2*kk]   = *(const f32x4*)(pB + kk*32);
      rB[2*kk+1] = *(const f32x4*)(pB + kk*32 + 4);
    }
  }

  bf16x8 ahA[4], alA[4], ahB[4], alB[4];
  #pragma unroll
  for (int kk=0;kk<4;kk++){
    union{ short s[8]; bf16x8 v; } uh, ul;
    #pragma unroll
    for (int j=0;j<4;j++){
      splitb(rA[2*kk][j],   uh.s[j],   ul.s[j]);
      splitb(rA[2*kk+1][j], uh.s[4+j], ul.s[4+j]);
    }
    ahA[kk] = uh.v; alA[kk] = ul.v;
  }
  #pragma unroll
  for (int kk=0;kk<4;kk++){
    union{ short s[8]; bf16x8 v; } uh, ul;
    #pragma unroll
    for (int j=0;j<4;j++){
      splitb(rB[2*kk][j],   uh.s[j],   ul.s[j]);
      splitb(rB[2*kk+1][j], uh.s[4+j], ul.s[4+j]);
    }
    ahB[kk] = uh.v; alB[kk] = ul.v;
  }

  f32x4 accA[8], accB[8];
  #pragma unroll
  for (int n=0;n<8;n++){ accA[n] = (f32x4){0.f,0.f,0.f,0.f}; accB[n] = (f32x4){0.f,0.f,0.f,0.f}; }

  #pragma unroll
  for (int kk=0;kk<4;kk++){
    #pragma unroll
    for (int n=0;n<8;n++){
      int row = n*16 + l15;
      int cofs = (kk*32 + lg*8) ^ ((l15&7)<<3);
      union{ s16x8 s; bf16x8 v; } wh, wl;
      wh.s = *(const s16x8*)(sW + row*128 + cofs);
      wl.s = *(const s16x8*)(sW + 16384 + row*128 + cofs);
      accA[n] = __builtin_amdgcn_mfma_f32_16x16x32_bf16(wh.v, ahA[kk], accA[n], 0, 0, 0);
      accA[n] = __builtin_amdgcn_mfma_f32_16x16x32_bf16(wh.v, alA[kk], accA[n], 0, 0, 0);
      accA[n] = __builtin_amdgcn_mfma_f32_16x16x32_bf16(wl.v, ahA[kk], accA[n], 0, 0, 0);
      accB[n] = __builtin_amdgcn_mfma_f32_16x16x32_bf16(wh.v, ahB[kk], accB[n], 0, 0, 0);
      accB[n] = __builtin_amdgcn_mfma_f32_16x16x32_bf16(wh.v, alB[kk], accB[n], 0, 0, 0);
      accB[n] = __builtin_amdgcn_mfma_f32_16x16x32_bf16(wl.v, ahB[kk], accB[n], 0, 0, 0);
    }
  }

  // epilogue: C row = lg*4+reg -> h = n*16+lg*4+reg, col = l15 -> edge
  const float* bxA = bx + ((size_t)b*NV + svA)*NH;
  const float* cxA = cx + ((size_t)b*NV + dvA)*NH;
  const float* bxB = bx + ((size_t)b*NV + svB)*NH;
  const float* cxB = cx + ((size_t)b*NV + dvB)*NH;
  float* ehA = ehg + (size_t)eAc*NH;
  float* ehB = ehg + (size_t)eBc*NH;
  #pragma unroll
  for (int n=0;n<8;n++){
    int h0 = n*16 + lg*4;
    f32x4 ab4 = *(const f32x4*)(Ab + h0);
    f32x4 bA = *(const f32x4*)(bxA + h0);
    f32x4 cA = *(const f32x4*)(cxA + h0);
    f32x4 bB = *(const f32x4*)(bxB + h0);
    f32x4 cB = *(const f32x4*)(cxB + h0);
    f32x4 oA, oB;
    if (is_l0){
      f32x4 w4 = *(const f32x4*)(eWe + h0);
      f32x4 q4 = *(const f32x4*)(ebe + h0);
      #pragma unroll
      for (int j=0;j<4;j++){ oA[j] = evA*w4[j] + q4[j]; oB[j] = evB*w4[j] + q4[j]; }
    } else {
      oA = *(const f32x4*)(ehA + h0);
      oB = *(const f32x4*)(ehB + h0);
    }
    f32x4 nA, nB;
    #pragma unroll
    for (int j=0;j<4;j++){
      float vA = accA[n][j] + ab4[j] + bA[j] + cA[j];
      vA = vA > 0.f ? vA : 0.f;
      nA[j] = oA[j] + vA;
      float vB = accB[n][j] + ab4[j] + bB[j] + cB[j];
      vB = vB > 0.f ? vB : 0.f;
      nB[j] = oB[j] + vB;
    }
    if (eA < NE) *(f32x4*)(ehA + h0) = nA;
    if (eB < NE) *(f32x4*)(ehB + h0) = nB;
  }
}

// ---------------- output: sigmoid(relu(eh@W1+b1)@W2+b2) ----------------
// takes BASE Wt (matrix 3 = hi, 7 = lo); W1 hi+lo both in LDS
__global__ __launch_bounds__(256) void k_out(
    const float* __restrict__ eh, const short* __restrict__ Wt,
    const float* __restrict__ b1, const float* __restrict__ W2,
    const float* __restrict__ b2, float* __restrict__ out)
{
  __shared__ short sW[2*NH*NH];
  const short* Whi = Wt + 3*NH*NH;
  const short* Wlo = Wt + 7*NH*NH;
  {
    #pragma unroll
    for (int i=0;i<16;i++){
      int sidx = (threadIdx.x + i*256)*8;
      int p = sidx >> 14, r = sidx & 16383;
      int hh = r >> 7, kw = r & 127;
      const short* src = p ? Wlo : Whi;
      s16x8 vv = *(const s16x8*)(src + r);
      *(s16x8*)(sW + p*16384 + hh*128 + (kw ^ ((hh&7)<<3))) = vv;
    }
  }
  __syncthreads();

  int blk  = blockIdx.x % EBLK;
  int b    = blockIdx.x / EBLK;
  int wave = threadIdx.x >> 6;
  int lane = threadIdx.x & 63;
  int l15 = lane & 15, lg = lane >> 4;
  int eA = blk*128 + wave*32 + l15;
  int eB = eA + 16;
  int eAc = eA < NE ? eA : NE-1;
  int eBc = eB < NE ? eB : NE-1;
  const float* ehg = eh + (size_t)b*NE*NH;

  const float* pA = ehg + (size_t)eAc*NH + lg*8;
  const float* pB = ehg + (size_t)eBc*NH + lg*8;
  f32x4 rA[8], rB[8];
  #pragma unroll
  for (int kk=0;kk<4;kk++){
    rA[2*kk]   = *(const f32x4*)(pA + kk*32);
    rA[2*kk+1] = *(const f32x4*)(pA + kk*32 + 4);
  }
  #pragma unroll
  for (int kk=0;kk<4;kk++){
    rB[2*kk]   = *(const f32x4*)(pB + kk*32);
    rB[2*kk+1] = *(const f32x4*)(pB + kk*32 + 4);
  }

  bf16x8 ahA[4], alA[4], ahB[4], alB[4];
  #pragma unroll
  for (int kk=0;kk<4;kk++){
    union{ short s[8]; bf16x8 v; } uh, ul;
    #pragma unroll
    for (int j=0;j<4;j++){
      splitb(rA[2*kk][j],   uh.s[j],   ul.s[j]);
      splitb(rA[2*kk+1][j], uh.s[4+j], ul.s[4+j]);
    }
    ahA[kk] = uh.v; alA[kk] = ul.v;
  }
  #pragma unroll
  for (int kk=0;kk<4;kk++){
    union{ short s[8]; bf16x8 v; } uh, ul;
    #pragma unroll
    for (int j=0;j<4;j++){
      splitb(rB[2*kk][j],   uh.s[j],   ul.s[j]);
      splitb(rB[2*kk+1][j], uh.s[4+j], ul.s[4+j]);
    }
    ahB[kk] = uh.v; alB[kk] = ul.v;
  }

  f32x4 accA[8], accB[8];
  #pragma unroll
  for (int n=0;n<8;n++){ accA[n] = (f32x4){0.f,0.f,0.f,0.f}; accB[n] = (f32x4){0.f,0.f,0.f,0.f}; }
  #pragma unroll
  for (int kk=0;kk<4;kk++){
    #pragma unroll
    for (int n=0;n<8;n++){
      int row = n*16 + l15;
      int cofs = (kk*32 + lg*8) ^ ((l15&7)<<3);
      union{ s16x8 s; bf16x8 v; } wh, wl;
      wh.s = *(const s16x8*)(sW + row*128 + cofs);
      wl.s = *(const s16x8*)(sW + 16384 + row*128 + cofs);
      accA[n] = __builtin_amdgcn_mfma_f32_16x16x32_bf16(wh.v, ahA[kk], accA[n], 0, 0, 0);
      accA[n] = __builtin_amdgcn_mfma_f32_16x16x32_bf16(wh.v, alA[kk], accA[n], 0, 0, 0);
      accA[n] = __builtin_amdgcn_mfma_f32_16x16x32_bf16(wl.v, ahA[kk], accA[n], 0, 0, 0);
      accB[n] = __builtin_amdgcn_mfma_f32_16x16x32_bf16(wh.v, ahB[kk], accB[n], 0, 0, 0);
      accB[n] = __builtin_amdgcn_mfma_f32_16x16x32_bf16(wh.v, alB[kk], accB[n], 0, 0, 0);
      accB[n] = __builtin_amdgcn_mfma_f32_16x16x32_bf16(wl.v, ahB[kk], accB[n], 0, 0, 0);
    }
  }

  float p0A = 0.f, p1A = 0.f, p0B = 0.f, p1B = 0.f;
  #pragma unroll
  for (int n=0;n<8;n++){
    int h0 = n*16 + lg*4;
    f32x4 b14 = *(const f32x4*)(b1 + h0);
    f32x4 wA  = *(const f32x4*)(W2 + h0*2);
    f32x4 wB  = *(const f32x4*)(W2 + h0*2 + 4);
    #pragma unroll
    for (int j=0;j<4;j++){
      float w20 = (j<2) ? wA[2*j]   : wB[2*(j-2)];
      float w21 = (j<2) ? wA[2*j+1] : wB[2*(j-2)+1];
      float hA = accA[n][j] + b14[j]; hA = hA > 0.f ? hA : 0.f;
      float hB = accB[n][j] + b14[j]; hB = hB > 0.f ? hB : 0.f;
      p0A += hA*w20; p1A += hA*w21;
      p0B += hB*w20; p1B += hB*w21;
    }
  }
  p0A += __shfl_xor(p0A, 16, 64); p0A += __shfl_xor(p0A, 32, 64);
  p1A += __shfl_xor(p1A, 16, 64); p1A += __shfl_xor(p1A, 32, 64);
  p0B += __shfl_xor(p0B, 16, 64); p0B += __shfl_xor(p0B, 32, 64);
  p1B += __shfl_xor(p1B, 16, 64); p1B += __shfl_xor(p1B, 32, 64);
  if (lg == 0){
    float bb0 = b2[0], bb1 = b2[1];
    if (eA < NE){
      float2 r; r.x = sigmoidf_(p0A + bb0); r.y = sigmoidf_(p1A + bb1);
      *(float2*)(out + ((size_t)b*NE + eA)*2) = r;
    }
    if (eB < NE){
      float2 r; r.x = sigmoidf_(p0B + bb0); r.y = sigmoidf_(p1B + bb1);
      *(float2*)(out + ((size_t)b*NE + eB)*2) = r;
    }
  }
}

extern "C" void kernel_launch(void* const* d_in, const int* in_sizes, int n_in,
                              void* d_out, int out_size, void* d_ws, size_t ws_size,
                              hipStream_t stream)
{
  const float* x   = (const float*)d_in[0];
  const float* e   = (const float*)d_in[1];
  const int*   ei  = (const int*)d_in[2];
  const float* nW  = (const float*)d_in[3];
  const float* nb  = (const float*)d_in[4];
  const float* eW  = (const float*)d_in[5];
  const float* eb  = (const float*)d_in[6];
  const float* UW  = (const float*)d_in[7];
  const float* Ub  = (const float*)d_in[8];
  const float* VW  = (const float*)d_in[9];
  const float* Vb  = (const float*)d_in[10];
  const float* AW  = (const float*)d_in[11];
  const float* Ab  = (const float*)d_in[12];
  const float* BW  = (const float*)d_in[13];
  const float* Bb  = (const float*)d_in[14];
  const float* CW  = (const float*)d_in[15];
  const float* Cb  = (const float*)d_in[16];
  const float* oW1 = (const float*)d_in[17];
  const float* ob1 = (const float*)d_in[18];
  const float* oW2 = (const float*)d_in[19];
  const float* ob2 = (const float*)d_in[20];
  float* out = (float*)d_out;

  char* ws = (char*)d_ws;
  size_t off = 0;
  auto alloc = [&](size_t bytes)->char*{
    char* p = ws + off;
    off += (bytes + 255) & ~(size_t)255;
    return p;
  };
  float* eh     = (float*)alloc((size_t)NB*NE*NH*4);
  float* xh     = (float*)alloc((size_t)NB*NV*NH*4);
  float* vx     = (float*)alloc((size_t)NB*NV*NH*4);
  float* bx     = (float*)alloc((size_t)NB*NV*NH*4);
  float* cx     = (float*)alloc((size_t)NB*NV*NH*4);
  float* ux     = (float*)alloc((size_t)NB*NV*NH*4);
  float* agg    = (float*)alloc((size_t)2*NB*NV*NH*4);
  short* Wt     = (short*)alloc((size_t)8*NH*NH*2);
  int* counts   = (int*)alloc((size_t)NB*NV*4);
  int* cursor   = (int*)alloc((size_t)NB*NV*4);
  int* offs     = (int*)alloc((size_t)NB*(NV+1)*4);
  int* csr      = (int*)alloc((size_t)NB*NE*4);
  (void)ws_size; (void)in_sizes; (void)n_in; (void)out_size;

  k_embed_nodes<<<(NB*NV*NH+255)/256, 256, 0, stream>>>(x, nW, nb, xh);
  k_trans_w<<<4, 256, 0, stream>>>(AW, oW1, Wt);
  k_zero<<<(NB*NV+255)/256, 256, 0, stream>>>(counts, NB*NV);
  k_count<<<(NB*NE+255)/256, 256, 0, stream>>>(ei, counts);
  k_scan<<<NB, 64, 0, stream>>>(counts, offs, cursor);
  k_scatter<<<(NB*NE+255)/256, 256, 0, stream>>>(ei, cursor, csr);

  for (int l=0; l<NL; l++){
    k_node_mm<<<NB*NV, 256, 0, stream>>>(xh, agg,
        VW + l*NH*NH, Vb + l*NH, BW + l*NH*NH, Bb + l*NH,
        CW + l*NH*NH, Cb + l*NH, UW + l*NH*NH, Ub + l*NH,
        vx, bx, cx, ux, l > 0 ? 1 : 0);
    if (l < NL-1)   // agg of the last layer only feeds dead xh_3
      k_agg<<<NB*NV*2, 128, 0, stream>>>(eh, e, eW, eb, vx, ei, csr, offs, agg, l==0 ? 1 : 0);
    k_edge_update<<<NB*EBLK, 256, 0, stream>>>(eh, Wt + l*NH*NH, Ab + l*NH, bx, cx, ei,
                                               e, eW, eb, l==0 ? 1 : 0);
  }
  k_out<<<NB*EBLK, 256, 0, stream>>>(eh, Wt, ob1, oW2, ob2, out);
}

// Round 7
// 554.730 us; speedup vs baseline: 2.0481x; 1.0004x over previous
//
#include <hip/hip_runtime.h>
#include <hip/hip_bf16.h>

#define NB 8
#define NV 200
#define NE 40000
#define NH 128
#define NL 3
#define EBLK 157        // ceil(NE/256): 256 edges per block (8 waves x 2 tiles of 16)

typedef __attribute__((ext_vector_type(8))) __bf16 bf16x8;
typedef __attribute__((ext_vector_type(8))) short s16x8;
typedef __attribute__((ext_vector_type(4))) short s16x4;
typedef __attribute__((ext_vector_type(4))) float f32x4;

__device__ inline float sigmoidf_(float x){ return 1.0f/(1.0f + __expf(-x)); }

__device__ inline short f2b(float f){
  union{ float f; unsigned u; } v; v.f = f;
  unsigned u = v.u;
  u += 0x7fffu + ((u >> 16) & 1u);
  return (short)(u >> 16);
}
__device__ inline float b2f(short s){
  union{ unsigned u; float f; } v; v.u = ((unsigned)(unsigned short)s) << 16;
  return v.f;
}
__device__ inline void splitb(float x, short &hi, short &lo){
  hi = f2b(x);
  lo = f2b(x - b2f(hi));
}

// ---------------- embed nodes ----------------
__global__ __launch_bounds__(256) void k_embed_nodes(
    const float* __restrict__ x, const float* __restrict__ nW,
    const float* __restrict__ nb, float* __restrict__ xh)
{
  int i = blockIdx.x*256 + threadIdx.x;
  if (i >= NB*NV*NH) return;
  int h  = i & (NH-1);
  int bv = i >> 7;
  xh[i] = x[bv*2+0]*nW[h] + x[bv*2+1]*nW[NH+h] + nb[h];
}

// ---------------- weight transpose to split bf16 (Wt[n][k] = W[k][n]) ----------------
// Wt + m*NH*NH -> hi of matrix m (0..2: A_W, 3: out_W1); Wt + (4+m)*NH*NH -> lo
__global__ __launch_bounds__(256) void k_trans_w(
    const float* __restrict__ AW, const float* __restrict__ oW1,
    short* __restrict__ Wt)
{
  int m = blockIdx.x;                         // 0..3
  const float* src = (m < 3) ? (AW + m*NH*NH) : oW1;
  short* dhi = Wt + (size_t)m*NH*NH;
  short* dlo = Wt + (size_t)(4+m)*NH*NH;
  for (int i = threadIdx.x; i < NH*NH; i += 256){
    int n = i >> 7, k = i & 127;
    short hi, lo;
    splitb(src[k*NH + n], hi, lo);
    dhi[i] = hi; dlo[i] = lo;
  }
}

// ---------------- CSR build ----------------
__global__ __launch_bounds__(256) void k_zero(int* __restrict__ p, int n){
  int i = blockIdx.x*256 + threadIdx.x;
  if (i < n) p[i] = 0;
}

__global__ __launch_bounds__(256) void k_count(const int* __restrict__ ei, int* __restrict__ counts){
  int i = blockIdx.x*256 + threadIdx.x;
  if (i >= NB*NE) return;
  int b = i / NE, e = i % NE;
  int dv = ei[b*2*NE + NE + e];
  atomicAdd(&counts[b*NV + dv], 1);
}

__global__ void k_scan(const int* __restrict__ counts, int* __restrict__ offs, int* __restrict__ cursor){
  int b = blockIdx.x;
  if (threadIdx.x == 0){
    int run = 0;
    for (int v=0; v<NV; v++){
      offs[b*(NV+1)+v] = run;
      cursor[b*NV+v]   = run;
      run += counts[b*NV+v];
    }
    offs[b*(NV+1)+NV] = run;
  }
}

__global__ __launch_bounds__(256) void k_scatter(const int* __restrict__ ei, int* __restrict__ cursor, int* __restrict__ csr){
  int i = blockIdx.x*256 + threadIdx.x;
  if (i >= NB*NE) return;
  int b = i / NE, e = i % NE;
  int dv = ei[b*2*NE + NE + e];
  int pos = atomicAdd(&cursor[b*NV + dv], 1);
  csr[(size_t)b*NE + pos] = e;
}

// ---------------- node: (optional xh update from prev layer) + 4 matmuls ----------------
__global__ __launch_bounds__(256) void k_node_mm(
    float* __restrict__ xh, const float* __restrict__ agg,
    const float* __restrict__ VWl, const float* __restrict__ Vbl,
    const float* __restrict__ BWl, const float* __restrict__ Bbl,
    const float* __restrict__ CWl, const float* __restrict__ Cbl,
    const float* __restrict__ UWl, const float* __restrict__ Ubl,
    float* __restrict__ vx, float* __restrict__ bx,
    float* __restrict__ cx, float* __restrict__ ux,
    int do_update)
{
  __shared__ float sx[NH];
  int b = blockIdx.x / NV, v = blockIdx.x % NV;
  size_t row = (size_t)b*NV + v;
  float* xr = xh + row*NH;
  int ht = threadIdx.x;
  if (ht < NH){
    float xv = xr[ht];
    if (do_update){
      float u = ux[row*NH + ht];
      #pragma unroll
      for (int p=0;p<4;p++) u += agg[(size_t)p*NB*NV*NH + row*NH + ht];
      xv += u > 0.f ? u : 0.f;
      xr[ht] = xv;
    }
    sx[ht] = xv;
  }
  __syncthreads();
  #pragma unroll
  for (int pass=0; pass<2; pass++){
    int t = threadIdx.x + pass*256;
    int mat = t >> 7, h = t & 127;
    const float* W = (mat==0) ? VWl : (mat==1) ? BWl : (mat==2) ? CWl : UWl;
    const float* bs = (mat==0) ? Vbl : (mat==1) ? Bbl : (mat==2) ? Cbl : Ubl;
    float* op = (mat==0) ? vx : (mat==1) ? bx : (mat==2) ? cx : ux;
    float acc = bs[h];
    #pragma unroll 8
    for (int k=0;k<NH;k++) acc += sx[k]*W[k*NH + h];
    op[row*NH + h] = acc;
  }
}

// ---------------- aggregation (4 partial blocks per node) ----------------
__global__ __launch_bounds__(128) void k_agg(
    const float* __restrict__ eh, const float* __restrict__ evec,
    const float* __restrict__ eWe, const float* __restrict__ ebe,
    const float* __restrict__ vx, const int* __restrict__ ei,
    const int* __restrict__ csr, const int* __restrict__ offs,
    float* __restrict__ agg, int is_l0)
{
  int part = blockIdx.x & 3;
  int bv   = blockIdx.x >> 2;
  int b = bv / NV, v = bv % NV;
  int h = threadIdx.x;
  const int* srcp  = ei + b*2*NE;
  const int* csrg  = csr + (size_t)b*NE;
  const float* ehg = eh + (size_t)b*NE*NH;
  const float* evg = evec + (size_t)b*NE;
  const float* vxg = vx + (size_t)b*NV*NH;
  float wh = eWe[h], bh = ebe[h];
  int beg = offs[b*(NV+1)+v], end = offs[b*(NV+1)+v+1];
  int len = end - beg;
  int i    = beg + ((len*part) >> 2);
  int stop = beg + ((len*(part+1)) >> 2);
  float acc = 0.f;
  for (; i+8 <= stop; i += 8){
    int   eb[8], sb[8];
    float a[8], w[8];
    #pragma unroll
    for (int j=0;j<8;j++) eb[j] = csrg[i+j];
    #pragma unroll
    for (int j=0;j<8;j++) sb[j] = srcp[eb[j]];
    if (is_l0){
      #pragma unroll
      for (int j=0;j<8;j++) a[j] = evg[eb[j]]*wh + bh;
    } else {
      #pragma unroll
      for (int j=0;j<8;j++) a[j] = ehg[(size_t)eb[j]*NH + h];
    }
    #pragma unroll
    for (int j=0;j<8;j++) w[j] = vxg[sb[j]*NH + h];
    #pragma unroll
    for (int j=0;j<8;j++) acc += sigmoidf_(a[j]) * w[j];
  }
  for (; i < stop; i++){
    int e0 = csrg[i]; int s0 = srcp[e0];
    float a = is_l0 ? (evg[e0]*wh + bh) : ehg[(size_t)e0*NH+h];
    acc += sigmoidf_(a) * vxg[s0*NH+h];
  }
  agg[((size_t)part*NB*NV + (size_t)b*NV + v)*NH + h] = acc;
}

// ---------------- edge update (layers 0,1): eh_new = eh_old + relu(eh_old@A_W + ...) ------
// 512 threads (8 waves x 32 edges). W hi+lo in LDS (64KB, XOR swizzle).
__global__ __launch_bounds__(512) void k_edge_update(
    float* __restrict__ eh, const short* __restrict__ Wt,
    const float* __restrict__ Ab, const float* __restrict__ bx,
    const float* __restrict__ cx, const int* __restrict__ ei,
    const float* __restrict__ evec, const float* __restrict__ eWe,
    const float* __restrict__ ebe, int is_l0)
{
  __shared__ short sW[2*NH*NH];         // 64 KB: [0..16383]=hi, [16384..]=lo
  const short* Whi = Wt;
  const short* Wlo = Wt + 4*NH*NH;
  {
    #pragma unroll
    for (int i=0;i<8;i++){
      int sidx = (threadIdx.x + i*512)*8;       // short index 0..32767
      int p = sidx >> 14, r = sidx & 16383;
      int hh = r >> 7, kw = r & 127;
      const short* src = p ? Wlo : Whi;
      s16x8 vv = *(const s16x8*)(src + r);
      *(s16x8*)(sW + p*16384 + hh*128 + (kw ^ ((hh&7)<<3))) = vv;
    }
  }
  __syncthreads();

  int blk  = blockIdx.x % EBLK;
  int b    = blockIdx.x / EBLK;
  int wave = threadIdx.x >> 6;
  int lane = threadIdx.x & 63;
  int l15 = lane & 15, lg = lane >> 4;
  int eA = blk*256 + wave*32 + l15;
  int eB = eA + 16;
  int eAc = eA < NE ? eA : NE-1;
  int eBc = eB < NE ? eB : NE-1;
  float* ehg = eh + (size_t)b*NE*NH;
  const int* srcp = ei + b*2*NE;
  int svA = srcp[eAc], dvA = srcp[NE+eAc];
  int svB = srcp[eBc], dvB = srcp[NE+eBc];

  float evA = 0.f, evB = 0.f;
  f32x4 rA[8], rB[8];
  if (is_l0){
    evA = evec[(size_t)b*NE + eAc];
    evB = evec[(size_t)b*NE + eBc];
    #pragma unroll
    for (int kk=0;kk<4;kk++){
      f32x4 w0 = *(const f32x4*)(eWe + kk*32 + lg*8);
      f32x4 w1 = *(const f32x4*)(eWe + kk*32 + lg*8 + 4);
      f32x4 q0 = *(const f32x4*)(ebe + kk*32 + lg*8);
      f32x4 q1 = *(const f32x4*)(ebe + kk*32 + lg*8 + 4);
      #pragma unroll
      for (int j=0;j<4;j++){
        rA[2*kk][j]   = evA*w0[j] + q0[j];
        rA[2*kk+1][j] = evA*w1[j] + q1[j];
        rB[2*kk][j]   = evB*w0[j] + q0[j];
        rB[2*kk+1][j] = evB*w1[j] + q1[j];
      }
    }
  } else {
    const float* pA = ehg + (size_t)eAc*NH + lg*8;
    const float* pB = ehg + (size_t)eBc*NH + lg*8;
    #pragma unroll
    for (int kk=0;kk<4;kk++){
      rA[2*kk]   = *(const f32x4*)(pA + kk*32);
      rA[2*kk+1] = *(const f32x4*)(pA + kk*32 + 4);
    }
    #pragma unroll
    for (int kk=0;kk<4;kk++){
      rB[2*kk]   = *(const f32x4*)(pB + kk*32);
      rB[2*kk+1] = *(const f32x4*)(pB + kk*32 + 4);
    }
  }

  bf16x8 ahA[4], alA[4], ahB[4], alB[4];
  #pragma unroll
  for (int kk=0;kk<4;kk++){
    union{ short s[8]; bf16x8 v; } uh, ul;
    #pragma unroll
    for (int j=0;j<4;j++){
      splitb(rA[2*kk][j],   uh.s[j],   ul.s[j]);
      splitb(rA[2*kk+1][j], uh.s[4+j], ul.s[4+j]);
    }
    ahA[kk] = uh.v; alA[kk] = ul.v;
  }
  #pragma unroll
  for (int kk=0;kk<4;kk++){
    union{ short s[8]; bf16x8 v; } uh, ul;
    #pragma unroll
    for (int j=0;j<4;j++){
      splitb(rB[2*kk][j],   uh.s[j],   ul.s[j]);
      splitb(rB[2*kk+1][j], uh.s[4+j], ul.s[4+j]);
    }
    ahB[kk] = uh.v; alB[kk] = ul.v;
  }

  f32x4 accA[8], accB[8];
  #pragma unroll
  for (int n=0;n<8;n++){ accA[n] = (f32x4){0.f,0.f,0.f,0.f}; accB[n] = (f32x4){0.f,0.f,0.f,0.f}; }

  #pragma unroll
  for (int kk=0;kk<4;kk++){
    #pragma unroll
    for (int n=0;n<8;n++){
      int row = n*16 + l15;
      int cofs = (kk*32 + lg*8) ^ ((l15&7)<<3);
      union{ s16x8 s; bf16x8 v; } wh, wl;
      wh.s = *(const s16x8*)(sW + row*128 + cofs);
      wl.s = *(const s16x8*)(sW + 16384 + row*128 + cofs);
      accA[n] = __builtin_amdgcn_mfma_f32_16x16x32_bf16(wh.v, ahA[kk], accA[n], 0, 0, 0);
      accA[n] = __builtin_amdgcn_mfma_f32_16x16x32_bf16(wh.v, alA[kk], accA[n], 0, 0, 0);
      accA[n] = __builtin_amdgcn_mfma_f32_16x16x32_bf16(wl.v, ahA[kk], accA[n], 0, 0, 0);
      accB[n] = __builtin_amdgcn_mfma_f32_16x16x32_bf16(wh.v, ahB[kk], accB[n], 0, 0, 0);
      accB[n] = __builtin_amdgcn_mfma_f32_16x16x32_bf16(wh.v, alB[kk], accB[n], 0, 0, 0);
      accB[n] = __builtin_amdgcn_mfma_f32_16x16x32_bf16(wl.v, ahB[kk], accB[n], 0, 0, 0);
    }
  }

  const float* bxA = bx + ((size_t)b*NV + svA)*NH;
  const float* cxA = cx + ((size_t)b*NV + dvA)*NH;
  const float* bxB = bx + ((size_t)b*NV + svB)*NH;
  const float* cxB = cx + ((size_t)b*NV + dvB)*NH;
  float* ehA = ehg + (size_t)eAc*NH;
  float* ehB = ehg + (size_t)eBc*NH;
  #pragma unroll
  for (int n=0;n<8;n++){
    int h0 = n*16 + lg*4;
    f32x4 ab4 = *(const f32x4*)(Ab + h0);
    f32x4 bA = *(const f32x4*)(bxA + h0);
    f32x4 cA = *(const f32x4*)(cxA + h0);
    f32x4 bB = *(const f32x4*)(bxB + h0);
    f32x4 cB = *(const f32x4*)(cxB + h0);
    f32x4 oA, oB;
    if (is_l0){
      f32x4 w4 = *(const f32x4*)(eWe + h0);
      f32x4 q4 = *(const f32x4*)(ebe + h0);
      #pragma unroll
      for (int j=0;j<4;j++){ oA[j] = evA*w4[j] + q4[j]; oB[j] = evB*w4[j] + q4[j]; }
    } else {
      oA = *(const f32x4*)(ehA + h0);
      oB = *(const f32x4*)(ehB + h0);
    }
    f32x4 nA, nB;
    #pragma unroll
    for (int j=0;j<4;j++){
      float vA = accA[n][j] + ab4[j] + bA[j] + cA[j];
      vA = vA > 0.f ? vA : 0.f;
      nA[j] = oA[j] + vA;
      float vB = accB[n][j] + ab4[j] + bB[j] + cB[j];
      vB = vB > 0.f ? vB : 0.f;
      nB[j] = oB[j] + vB;
    }
    if (eA < NE) *(f32x4*)(ehA + h0) = nA;
    if (eB < NE) *(f32x4*)(ehB + h0) = nB;
  }
}

// ---------------- fused layer-2 edge update + output MLP ----------------
// Phase 1: eh3 = eh2 + relu(eh2@A_W2 + ...) kept in REGISTERS (never stored).
// Phase 2: restage W1 (k-permuted by sigma) into same LDS; B-fragment built from
// the lane's own eh3 registers (k-slot (kk,lg,j) <-> h = 32kk+16(j>>2)+4lg+(j&3));
// A and B share the same k-map so the permutation cancels.
__global__ __launch_bounds__(512) void k_edge_out(
    const float* __restrict__ eh, const short* __restrict__ Wt,
    const float* __restrict__ Ab, const float* __restrict__ bx,
    const float* __restrict__ cx, const int* __restrict__ ei,
    const float* __restrict__ b1, const float* __restrict__ W2,
    const float* __restrict__ b2, float* __restrict__ out)
{
  __shared__ short sW[2*NH*NH];         // 64 KB
  const short* Whi = Wt + 2*NH*NH;      // A_W[2] hi
  const short* Wlo = Wt + 6*NH*NH;      // A_W[2] lo
  {
    #pragma unroll
    for (int i=0;i<8;i++){
      int sidx = (threadIdx.x + i*512)*8;
      int p = sidx >> 14, r = sidx & 16383;
      int hh = r >> 7, kw = r & 127;
      const short* src = p ? Wlo : Whi;
      s16x8 vv = *(const s16x8*)(src + r);
      *(s16x8*)(sW + p*16384 + hh*128 + (kw ^ ((hh&7)<<3))) = vv;
    }
  }
  __syncthreads();

  int blk  = blockIdx.x % EBLK;
  int b    = blockIdx.x / EBLK;
  int wave = threadIdx.x >> 6;
  int lane = threadIdx.x & 63;
  int l15 = lane & 15, lg = lane >> 4;
  int eA = blk*256 + wave*32 + l15;
  int eB = eA + 16;
  int eAc = eA < NE ? eA : NE-1;
  int eBc = eB < NE ? eB : NE-1;
  const float* ehg = eh + (size_t)b*NE*NH;
  const int* srcp = ei + b*2*NE;
  int svA = srcp[eAc], dvA = srcp[NE+eAc];
  int svB = srcp[eBc], dvB = srcp[NE+eBc];

  const float* pA = ehg + (size_t)eAc*NH + lg*8;
  const float* pB = ehg + (size_t)eBc*NH + lg*8;
  f32x4 rA[8], rB[8];
  #pragma unroll
  for (int kk=0;kk<4;kk++){
    rA[2*kk]   = *(const f32x4*)(pA + kk*32);
    rA[2*kk+1] = *(const f32x4*)(pA + kk*32 + 4);
  }
  #pragma unroll
  for (int kk=0;kk<4;kk++){
    rB[2*kk]   = *(const f32x4*)(pB + kk*32);
    rB[2*kk+1] = *(const f32x4*)(pB + kk*32 + 4);
  }

  bf16x8 ahA[4], alA[4], ahB[4], alB[4];
  #pragma unroll
  for (int kk=0;kk<4;kk++){
    union{ short s[8]; bf16x8 v; } uh, ul;
    #pragma unroll
    for (int j=0;j<4;j++){
      splitb(rA[2*kk][j],   uh.s[j],   ul.s[j]);
      splitb(rA[2*kk+1][j], uh.s[4+j], ul.s[4+j]);
    }
    ahA[kk] = uh.v; alA[kk] = ul.v;
  }
  #pragma unroll
  for (int kk=0;kk<4;kk++){
    union{ short s[8]; bf16x8 v; } uh, ul;
    #pragma unroll
    for (int j=0;j<4;j++){
      splitb(rB[2*kk][j],   uh.s[j],   ul.s[j]);
      splitb(rB[2*kk+1][j], uh.s[4+j], ul.s[4+j]);
    }
    ahB[kk] = uh.v; alB[kk] = ul.v;
  }

  f32x4 accA[8], accB[8];
  #pragma unroll
  for (int n=0;n<8;n++){ accA[n] = (f32x4){0.f,0.f,0.f,0.f}; accB[n] = (f32x4){0.f,0.f,0.f,0.f}; }
  #pragma unroll
  for (int kk=0;kk<4;kk++){
    #pragma unroll
    for (int n=0;n<8;n++){
      int row = n*16 + l15;
      int cofs = (kk*32 + lg*8) ^ ((l15&7)<<3);
      union{ s16x8 s; bf16x8 v; } wh, wl;
      wh.s = *(const s16x8*)(sW + row*128 + cofs);
      wl.s = *(const s16x8*)(sW + 16384 + row*128 + cofs);
      accA[n] = __builtin_amdgcn_mfma_f32_16x16x32_bf16(wh.v, ahA[kk], accA[n], 0, 0, 0);
      accA[n] = __builtin_amdgcn_mfma_f32_16x16x32_bf16(wh.v, alA[kk], accA[n], 0, 0, 0);
      accA[n] = __builtin_amdgcn_mfma_f32_16x16x32_bf16(wl.v, ahA[kk], accA[n], 0, 0, 0);
      accB[n] = __builtin_amdgcn_mfma_f32_16x16x32_bf16(wh.v, ahB[kk], accB[n], 0, 0, 0);
      accB[n] = __builtin_amdgcn_mfma_f32_16x16x32_bf16(wh.v, alB[kk], accB[n], 0, 0, 0);
      accB[n] = __builtin_amdgcn_mfma_f32_16x16x32_bf16(wl.v, ahB[kk], accB[n], 0, 0, 0);
    }
  }

  // eh3 in registers: nA[n][j] = eh3[edge eA][h = 16n + 4lg + j]
  f32x4 nAr[8], nBr[8];
  const float* bxA = bx + ((size_t)b*NV + svA)*NH;
  const float* cxA = cx + ((size_t)b*NV + dvA)*NH;
  const float* bxB = bx + ((size_t)b*NV + svB)*NH;
  const float* cxB = cx + ((size_t)b*NV + dvB)*NH;
  const float* ehA = ehg + (size_t)eAc*NH;
  const float* ehB = ehg + (size_t)eBc*NH;
  #pragma unroll
  for (int n=0;n<8;n++){
    int h0 = n*16 + lg*4;
    f32x4 ab4 = *(const f32x4*)(Ab + h0);
    f32x4 bA = *(const f32x4*)(bxA + h0);
    f32x4 cA = *(const f32x4*)(cxA + h0);
    f32x4 oA = *(const f32x4*)(ehA + h0);
    f32x4 bB = *(const f32x4*)(bxB + h0);
    f32x4 cB = *(const f32x4*)(cxB + h0);
    f32x4 oB = *(const f32x4*)(ehB + h0);
    #pragma unroll
    for (int j=0;j<4;j++){
      float vA = accA[n][j] + ab4[j] + bA[j] + cA[j];
      vA = vA > 0.f ? vA : 0.f;
      nAr[n][j] = oA[j] + vA;
      float vB = accB[n][j] + ab4[j] + bB[j] + cB[j];
      vB = vB > 0.f ? vB : 0.f;
      nBr[n][j] = oB[j] + vB;
    }
  }

  // Phase 2: restage W1 with k-permutation sigma(c)=32kk+16(j>>2)+4lg+(j&3)
  __syncthreads();    // all phase-1 LDS reads done
  {
    const short* W1hi = Wt + 3*NH*NH;
    const short* W1lo = Wt + 7*NH*NH;
    #pragma unroll
    for (int i=0;i<16;i++){
      int qd = threadIdx.x + i*512;           // quad index 0..8191
      int p = qd >> 12, rr = qd & 4095;
      int row = rr >> 5;
      int c0 = (rr & 31) << 2;                // 0,4,...,124
      int kk = c0 >> 5, lgs = (c0 >> 3) & 3, jhi = (c0 & 7) >> 2;
      int base = 32*kk + 16*jhi + 4*lgs;      // sigma of the quad start
      const short* src = p ? W1lo : W1hi;
      s16x4 v = *(const s16x4*)(src + row*128 + base);
      *(s16x4*)(sW + p*16384 + row*128 + (c0 ^ ((row&7)<<3))) = v;
    }
  }
  __syncthreads();

  // B-fragments for W1 matmul from eh3 registers (static indices)
  bf16x8 qhA[4], qlA[4], qhB[4], qlB[4];
  #pragma unroll
  for (int kk=0;kk<4;kk++){
    union{ short s[8]; bf16x8 v; } uhA, ulA, uhB, ulB;
    #pragma unroll
    for (int j=0;j<8;j++){
      splitb(nAr[2*kk + (j>>2)][j&3], uhA.s[j], ulA.s[j]);
      splitb(nBr[2*kk + (j>>2)][j&3], uhB.s[j], ulB.s[j]);
    }
    qhA[kk] = uhA.v; qlA[kk] = ulA.v;
    qhB[kk] = uhB.v; qlB[kk] = ulB.v;
  }

  f32x4 acc2A[8], acc2B[8];
  #pragma unroll
  for (int n=0;n<8;n++){ acc2A[n] = (f32x4){0.f,0.f,0.f,0.f}; acc2B[n] = (f32x4){0.f,0.f,0.f,0.f}; }
  #pragma unroll
  for (int kk=0;kk<4;kk++){
    #pragma unroll
    for (int n=0;n<8;n++){
      int row = n*16 + l15;
      int cofs = (kk*32 + lg*8) ^ ((l15&7)<<3);
      union{ s16x8 s; bf16x8 v; } wh, wl;
      wh.s = *(const s16x8*)(sW + row*128 + cofs);
      wl.s = *(const s16x8*)(sW + 16384 + row*128 + cofs);
      acc2A[n] = __builtin_amdgcn_mfma_f32_16x16x32_bf16(wh.v, qhA[kk], acc2A[n], 0, 0, 0);
      acc2A[n] = __builtin_amdgcn_mfma_f32_16x16x32_bf16(wh.v, qlA[kk], acc2A[n], 0, 0, 0);
      acc2A[n] = __builtin_amdgcn_mfma_f32_16x16x32_bf16(wl.v, qhA[kk], acc2A[n], 0, 0, 0);
      acc2B[n] = __builtin_amdgcn_mfma_f32_16x16x32_bf16(wh.v, qhB[kk], acc2B[n], 0, 0, 0);
      acc2B[n] = __builtin_amdgcn_mfma_f32_16x16x32_bf16(wh.v, qlB[kk], acc2B[n], 0, 0, 0);
      acc2B[n] = __builtin_amdgcn_mfma_f32_16x16x32_bf16(wl.v, qhB[kk], acc2B[n], 0, 0, 0);
    }
  }

  // W2 reduction + sigmoid
  float p0A = 0.f, p1A = 0.f, p0B = 0.f, p1B = 0.f;
  #pragma unroll
  for (int n=0;n<8;n++){
    int h0 = n*16 + lg*4;
    f32x4 b14 = *(const f32x4*)(b1 + h0);
    f32x4 wA  = *(const f32x4*)(W2 + h0*2);
    f32x4 wB  = *(const f32x4*)(W2 + h0*2 + 4);
    #pragma unroll
    for (int j=0;j<4;j++){
      float w20 = (j<2) ? wA[2*j]   : wB[2*(j-2)];
      float w21 = (j<2) ? wA[2*j+1] : wB[2*(j-2)+1];
      float hA = acc2A[n][j] + b14[j]; hA = hA > 0.f ? hA : 0.f;
      float hB = acc2B[n][j] + b14[j]; hB = hB > 0.f ? hB : 0.f;
      p0A += hA*w20; p1A += hA*w21;
      p0B += hB*w20; p1B += hB*w21;
    }
  }
  p0A += __shfl_xor(p0A, 16, 64); p0A += __shfl_xor(p0A, 32, 64);
  p1A += __shfl_xor(p1A, 16, 64); p1A += __shfl_xor(p1A, 32, 64);
  p0B += __shfl_xor(p0B, 16, 64); p0B += __shfl_xor(p0B, 32, 64);
  p1B += __shfl_xor(p1B, 16, 64); p1B += __shfl_xor(p1B, 32, 64);
  if (lg == 0){
    float bb0 = b2[0], bb1 = b2[1];
    if (eA < NE){
      float2 r; r.x = sigmoidf_(p0A + bb0); r.y = sigmoidf_(p1A + bb1);
      *(float2*)(out + ((size_t)b*NE + eA)*2) = r;
    }
    if (eB < NE){
      float2 r; r.x = sigmoidf_(p0B + bb0); r.y = sigmoidf_(p1B + bb1);
      *(float2*)(out + ((size_t)b*NE + eB)*2) = r;
    }
  }
}

extern "C" void kernel_launch(void* const* d_in, const int* in_sizes, int n_in,
                              void* d_out, int out_size, void* d_ws, size_t ws_size,
                              hipStream_t stream)
{
  const float* x   = (const float*)d_in[0];
  const float* e   = (const float*)d_in[1];
  const int*   ei  = (const int*)d_in[2];
  const float* nW  = (const float*)d_in[3];
  const float* nb  = (const float*)d_in[4];
  const float* eW  = (const float*)d_in[5];
  const float* eb  = (const float*)d_in[6];
  const float* UW  = (const float*)d_in[7];
  const float* Ub  = (const float*)d_in[8];
  const float* VW  = (const float*)d_in[9];
  const float* Vb  = (const float*)d_in[10];
  const float* AW  = (const float*)d_in[11];
  const float* Ab  = (const float*)d_in[12];
  const float* BW  = (const float*)d_in[13];
  const float* Bb  = (const float*)d_in[14];
  const float* CW  = (const float*)d_in[15];
  const float* Cb  = (const float*)d_in[16];
  const float* oW1 = (const float*)d_in[17];
  const float* ob1 = (const float*)d_in[18];
  const float* oW2 = (const float*)d_in[19];
  const float* ob2 = (const float*)d_in[20];
  float* out = (float*)d_out;

  char* ws = (char*)d_ws;
  size_t off = 0;
  auto alloc = [&](size_t bytes)->char*{
    char* p = ws + off;
    off += (bytes + 255) & ~(size_t)255;
    return p;
  };
  float* eh     = (float*)alloc((size_t)NB*NE*NH*4);
  float* xh     = (float*)alloc((size_t)NB*NV*NH*4);
  float* vx     = (float*)alloc((size_t)NB*NV*NH*4);
  float* bx     = (float*)alloc((size_t)NB*NV*NH*4);
  float* cx     = (float*)alloc((size_t)NB*NV*NH*4);
  float* ux     = (float*)alloc((size_t)NB*NV*NH*4);
  float* agg    = (float*)alloc((size_t)4*NB*NV*NH*4);
  short* Wt     = (short*)alloc((size_t)8*NH*NH*2);
  int* counts   = (int*)alloc((size_t)NB*NV*4);
  int* cursor   = (int*)alloc((size_t)NB*NV*4);
  int* offs     = (int*)alloc((size_t)NB*(NV+1)*4);
  int* csr      = (int*)alloc((size_t)NB*NE*4);
  (void)ws_size; (void)in_sizes; (void)n_in; (void)out_size;

  k_embed_nodes<<<(NB*NV*NH+255)/256, 256, 0, stream>>>(x, nW, nb, xh);
  k_trans_w<<<4, 256, 0, stream>>>(AW, oW1, Wt);
  k_zero<<<(NB*NV+255)/256, 256, 0, stream>>>(counts, NB*NV);
  k_count<<<(NB*NE+255)/256, 256, 0, stream>>>(ei, counts);
  k_scan<<<NB, 64, 0, stream>>>(counts, offs, cursor);
  k_scatter<<<(NB*NE+255)/256, 256, 0, stream>>>(ei, cursor, csr);

  for (int l=0; l<NL; l++){
    k_node_mm<<<NB*NV, 256, 0, stream>>>(xh, agg,
        VW + l*NH*NH, Vb + l*NH, BW + l*NH*NH, Bb + l*NH,
        CW + l*NH*NH, Cb + l*NH, UW + l*NH*NH, Ub + l*NH,
        vx, bx, cx, ux, l > 0 ? 1 : 0);
    if (l < NL-1)   // layer-2 agg only feeds dead xh_3
      k_agg<<<NB*NV*4, 128, 0, stream>>>(eh, e, eW, eb, vx, ei, csr, offs, agg, l==0 ? 1 : 0);
    if (l < NL-1)
      k_edge_update<<<NB*EBLK, 512, 0, stream>>>(eh, Wt + l*NH*NH, Ab + l*NH, bx, cx, ei,
                                                 e, eW, eb, l==0 ? 1 : 0);
    else
      k_edge_out<<<NB*EBLK, 512, 0, stream>>>(eh, Wt, Ab + l*NH, bx, cx, ei,
                                              ob1, oW2, ob2, out);
  }
}